// Round 8
// baseline (391.025 us; speedup 1.0000x reference)
//
#include <hip/hip_runtime.h>
#include <hip/hip_bf16.h>
#include <math.h>

#define NPTS 131072
#define DIM 32
#define MCL 256
#define NSTEP 18           // symmetric packing: 1 sq + 15 pair + 1 pair/lin + 1 lin/pad
#define BPTS 128           // points per block
#define THREADS 256

typedef __attribute__((ext_vector_type(8))) short s8v;    // 8 bf16 bit-patterns
typedef __attribute__((ext_vector_type(4))) short s4h;    // 4 bf16 (b64)
typedef __attribute__((ext_vector_type(4))) float f32x4;

__device__ __forceinline__ unsigned short f2bf(float f) {
    union { float f; unsigned u; } v; v.f = f;
    unsigned r = v.u + 0x7fffu + ((v.u >> 16) & 1u);   // RNE
    return (unsigned short)(r >> 16);
}

__device__ __forceinline__ void glds16(const void* g, void* l) {
    __builtin_amdgcn_global_load_lds(
        (const __attribute__((address_space(1))) unsigned int*)g,
        (__attribute__((address_space(3))) unsigned int*)l, 16, 0, 0);
}

// ---------------------------------------------------------------------------
// prep (256 threads/cluster): symmetric-packed G (bf16):
//  step 0           : c = E[k][k]                (squares; E = LL^T - I)
//  steps 1..15      : c = 2*E[k][(k+s)&31]       (pairs, circular diff s)
//  step 16, k<16    : c = 2*E[k][k+16]           (diff-16 pairs)
//  step 16, k>=16   : c = -2*Ac[k-16]            (linear)
//  step 17, k<16    : c = -2*Ac[k+16]            (linear)
//  step 17, k>=16   : c = 0                      (pad)
// G addr (shorts): s*8192 + (m>>4)*512 + (k>>3)*128 + (m&15)*8 + (k&7)
// logdet: register GE on wave 0 (col-per-lane, unrolled, no pivot).
// ---------------------------------------------------------------------------
__global__ __launch_bounds__(256) void gmm_prep(
    const float* __restrict__ center,
    const float* __restrict__ L,
    const float* __restrict__ weight,
    short* __restrict__ G,
    float* __restrict__ cst)
{
    const int m = blockIdx.x;
    const int t = threadIdx.x;
    __shared__ float Ls[DIM][DIM + 1];
    __shared__ float As[DIM][DIM + 1];
    __shared__ float Acs[DIM];
    __shared__ float red[DIM];

    const float* Lm = L + m * DIM * DIM;
    for (int k = t; k < DIM * DIM; k += 256)
        Ls[k >> 5][k & 31] = Lm[k];
    __syncthreads();

    // A = L L^T  (4 elems/thread)
    for (int idx = t; idx < DIM * DIM; idx += 256) {
        const int j = idx >> 5, l = idx & 31;
        float a = 0.f;
        #pragma unroll
        for (int d = 0; d < DIM; ++d) a = fmaf(Ls[j][d], Ls[l][d], a);
        As[j][l] = a;
    }
    __syncthreads();

    if (t < DIM) {
        float a = 0.f;
        #pragma unroll
        for (int l = 0; l < DIM; ++l) a = fmaf(As[t][l], center[m * DIM + l], a);
        Acs[t] = a;
        red[t] = a * center[m * DIM + t];
    }
    __syncthreads();

    const int mt = m >> 4, ml = m & 15;
    for (int idx = t; idx < NSTEP * 32; idx += 256) {
        const int s = idx >> 5, k = idx & 31;
        float c;
        if (s == 0)       c = As[k][k] - 1.0f;
        else if (s <= 15) c = 2.0f * As[k][(k + s) & 31];
        else if (s == 16) c = (k < 16) ? 2.0f * As[k][k + 16] : -2.0f * Acs[k - 16];
        else              c = (k < 16) ? -2.0f * Acs[k + 16] : 0.0f;
        G[s * 8192 + mt * 512 + (k >> 3) * 128 + ml * 8 + (k & 7)] = (short)f2bf(c);
    }

    if (t < 64) {
        // register GE, no pivot: lane j owns column j.
        float logdet = 0.f;
        if (t < DIM) {
            float col[DIM];
            #pragma unroll
            for (int r2 = 0; r2 < DIM; ++r2) col[r2] = Ls[r2][t];
            float prodabs = 1.0f;
            #pragma unroll
            for (int k = 0; k < DIM; ++k) {
                const float pv  = __shfl(col[k], k, 64);
                const float rpv = 1.0f / pv;
                const float cjk = col[k];
                #pragma unroll
                for (int t2 = k + 1; t2 < DIM; ++t2) {
                    const float f = __shfl(col[t2], k, 64) * rpv;
                    col[t2] = fmaf(-f, cjk, col[t2]);
                }
                prodabs *= fabsf(pv);
            }
            logdet = logf(prodabs);
        }

        float wsp = 0.f;
        for (int j = t; j < MCL; j += 64) wsp += fabsf(weight[j]);
        #pragma unroll
        for (int d2 = 1; d2 < 64; d2 <<= 1) wsp += __shfl_xor(wsp, d2, 64);

        if (t == 0) {
            float t3 = 0.f;
            #pragma unroll
            for (int j = 0; j < DIM; ++j) t3 += red[j];
            cst[m] = logf(fabsf(weight[m])) - logf(wsp) + logdet - 0.5f * t3;
        }
    }
}

// ---------------------------------------------------------------------------
// main kernel helpers: ALL element selection at compile time (R4 lesson).
// ---------------------------------------------------------------------------
template<int OFF2, int E>
__device__ __forceinline__ float welem(const s4h a0, const s4h a1, const s4h a2) {
    constexpr int idx = OFF2 + E;
    unsigned short h;
    if constexpr (idx < 4)      h = (unsigned short)a0[idx & 3];
    else if constexpr (idx < 8) h = (unsigned short)a1[idx & 3];
    else                        h = (unsigned short)a2[idx & 3];
    return __uint_as_float(((unsigned)h) << 16);
}

template<int S, int E>
__device__ __forceinline__ float xsel(const float (&xkr)[8], int kg) {
    if constexpr (S == 16)      return (kg < 2) ? xkr[E] : 1.0f;
    else if constexpr (S == 17) return (kg < 2) ? 1.0f : 0.0f;
    else                        return xkr[E];
}

template<int S, int Q, int OFF2>
__device__ __forceinline__ unsigned mkpair(const float (&xkr)[8], int kg,
                                           const s4h a0, const s4h a1, const s4h a2) {
    const float p0 = xsel<S, 2 * Q>(xkr, kg)     * welem<OFF2, 2 * Q>(a0, a1, a2);
    const float p1 = xsel<S, 2 * Q + 1>(xkr, kg) * welem<OFF2, 2 * Q + 1>(a0, a1, a2);
    __hip_bfloat162 h2 = __float22bfloat162_rn(make_float2(p0, p1));
    return *reinterpret_cast<unsigned*>(&h2);
}

// ---------------------------------------------------------------------------
// main: block = 128 pts x 256 cl, 4 waves, wave tile 64x128, K = 18*32 = 576.
// 2-buffer B staging, issue-early: stage(S+1) issued at START of step S, its
// 4 loads land during the step's MFMA work; vmcnt(0)+barrier at step end is
// then near-free. LDS 46.5 KB -> 3 blocks/CU = 12 waves = 3/SIMD (the R8
// occupancy lever; R6 was LDS-capped at 2 blocks).
// ---------------------------------------------------------------------------
template<int S>
__device__ __forceinline__ void stage(const short* __restrict__ G,
                                      short (&Bb)[2][8192], int w, int lane)
{
    constexpr int b = S & 1;
    const short* gs = G + (size_t)S * 8192 + w * 2048 + lane * 8;
    #pragma unroll
    for (int q = 0; q < 4; ++q)
        glds16(gs + q * 512, &Bb[b][w * 2048 + q * 512]);
}

template<int S>
__device__ __forceinline__ void k_step(
    const short* __restrict__ G,
    short (&Bb)[2][8192],
    const short* __restrict__ Xh,
    const int (&rowh)[4],
    const float (&xk)[4][8],
    f32x4 (&acc)[4][8],
    int w, int lane, int kg, int wc)
{
    constexpr int cb = S & 1;
    // issue next-tile loads FIRST; they land under this step's VALU+MFMA
    if constexpr (S + 1 < NSTEP) stage<S + 1>(G, Bb, w, lane);

    constexpr int shv  = (S == 17) ? 16 : S;
    constexpr int off2 = shv & 3;
    const int bq = ((kg * 8 + shv) & 31) & ~3;   // aligned 4-half base

    s8v af[4];
    #pragma unroll
    for (int i = 0; i < 4; ++i) {
        const short* xr = Xh + rowh[i] + bq;
        const s4h a0 = *(const s4h*)(xr);
        const s4h a1 = *(const s4h*)(xr + 4);
        s4h a2 = a1;
        if constexpr (off2 != 0) a2 = *(const s4h*)(xr + 8);

        union { s8v v; unsigned u[4]; } U;
        U.u[0] = mkpair<S, 0, off2>(xk[i], kg, a0, a1, a2);
        U.u[1] = mkpair<S, 1, off2>(xk[i], kg, a0, a1, a2);
        U.u[2] = mkpair<S, 2, off2>(xk[i], kg, a0, a1, a2);
        U.u[3] = mkpair<S, 3, off2>(xk[i], kg, a0, a1, a2);
        af[i] = U.v;
    }

    s8v bf[8];
    #pragma unroll
    for (int j = 0; j < 8; ++j)
        bf[j] = *(const s8v*)&Bb[cb][(wc * 8 + j) * 512 + lane * 8];
    #pragma unroll
    for (int i = 0; i < 4; ++i)
        #pragma unroll
        for (int j = 0; j < 8; ++j)
            acc[i][j] = __builtin_amdgcn_mfma_f32_16x16x32_bf16(
                af[i], bf[j], acc[i][j], 0, 0, 0);

    // stage(S+1) had the whole step to land; drain what's left + barrier.
    // (Next step's stage(S+2) writes Bb[cb], which everyone just finished
    // reading -- the barrier orders that reuse.)
    if constexpr (S + 1 < NSTEP)
        asm volatile("s_waitcnt vmcnt(0) lgkmcnt(0)\n\ts_barrier" ::: "memory");
}

template<int S>
__device__ __forceinline__ void k_loop(
    const short* __restrict__ G, short (&Bb)[2][8192],
    const short* __restrict__ Xh, const int (&rowh)[4],
    const float (&xk)[4][8], f32x4 (&acc)[4][8],
    int w, int lane, int kg, int wc)
{
    k_step<S>(G, Bb, Xh, rowh, xk, acc, w, lane, kg, wc);
    if constexpr (S + 1 < NSTEP)
        k_loop<S + 1>(G, Bb, Xh, rowh, xk, acc, w, lane, kg, wc);
}

__global__ __launch_bounds__(THREADS, 3) void gmm_mfma(
    const float* __restrict__ X,
    const short* __restrict__ G,
    const float* __restrict__ cstw,
    const float* __restrict__ thr,
    float* __restrict__ out)
{
    __shared__ __attribute__((aligned(16))) short Bb[2][8192];   // 32 KB
    __shared__ __attribute__((aligned(16))) short Xh[BPTS * 44]; // 11 KB
    __shared__ float nrm_s[BPTS];
    __shared__ float cst_s[MCL];
    __shared__ float lse_m[BPTS];
    __shared__ float lse_d[BPTS];

    const int tid  = threadIdx.x;
    const int lane = tid & 63;
    const int w    = tid >> 6;     // wave 0..3
    const int wr   = w & 1;        // row group: 64 points
    const int wc   = w >> 1;       // col group: 128 clusters
    const int r    = lane & 15;
    const int kg   = lane >> 4;
    const int P0   = blockIdx.x * BPTS;

    // stage B[0] (async)
    stage<0>(G, Bb, w, lane);

    // resident f32 x-slices straight from global (block's X slice is cache-hot)
    int rowh[4];
    float xk[4][8];
    #pragma unroll
    for (int i = 0; i < 4; ++i) {
        const int row = wr * 64 + i * 16 + r;
        rowh[i] = row * 44;
        const float4* xg = reinterpret_cast<const float4*>(
            X + (size_t)(P0 + row) * DIM + kg * 8);
        const float4 a = xg[0], b = xg[1];
        xk[i][0] = a.x; xk[i][1] = a.y; xk[i][2] = a.z; xk[i][3] = a.w;
        xk[i][4] = b.x; xk[i][5] = b.y; xk[i][6] = b.z; xk[i][7] = b.w;
    }

    // stage Xh (bf16, +8 dup for circular wrap) and row norms
    const int p = tid >> 1, hf = tid & 1;
    {
        const float4* Xg = reinterpret_cast<const float4*>(
            X + (size_t)(P0 + p) * DIM + hf * 16);
        float part = 0.f;
        #pragma unroll
        for (int q = 0; q < 4; ++q) {
            const float4 v = Xg[q];
            const int kb = hf * 16 + 4 * q;
            Xh[p * 44 + kb + 0] = (short)f2bf(v.x);
            Xh[p * 44 + kb + 1] = (short)f2bf(v.y);
            Xh[p * 44 + kb + 2] = (short)f2bf(v.z);
            Xh[p * 44 + kb + 3] = (short)f2bf(v.w);
            if (!hf && q < 2) {
                Xh[p * 44 + 32 + kb + 0] = (short)f2bf(v.x);
                Xh[p * 44 + 32 + kb + 1] = (short)f2bf(v.y);
                Xh[p * 44 + 32 + kb + 2] = (short)f2bf(v.z);
                Xh[p * 44 + 32 + kb + 3] = (short)f2bf(v.w);
            }
            part = fmaf(v.x, v.x, part); part = fmaf(v.y, v.y, part);
            part = fmaf(v.z, v.z, part); part = fmaf(v.w, v.w, part);
        }
        part += __shfl_xor(part, 1, 64);
        if (!hf) nrm_s[p] = part;
        cst_s[tid] = cstw[tid];
    }
    // Xh ds_writes drained + stage(0) landed; then everyone proceeds.
    asm volatile("s_waitcnt vmcnt(0) lgkmcnt(0)\n\ts_barrier" ::: "memory");

    f32x4 acc[4][8] = {};
    k_loop<0>(G, Bb, Xh, rowh, xk, acc, w, lane, kg, wc);

    // ---- epilogue: weighted LSE over this wave's 128 clusters
    float cstr[8];
    #pragma unroll
    for (int j = 0; j < 8; ++j)
        cstr[j] = cst_s[wc * 128 + j * 16 + r];

    float mx[16], sm[16];
    #pragma unroll
    for (int i = 0; i < 4; ++i)
        #pragma unroll
        for (int rg = 0; rg < 4; ++rg) {
            const int sl = i * 4 + rg;
            float m_ = -1e30f;
            #pragma unroll
            for (int j = 0; j < 8; ++j)
                m_ = fmaxf(m_, fmaf(acc[i][j][rg], -0.5f, cstr[j]));
            float s_ = 0.f;
            #pragma unroll
            for (int j = 0; j < 8; ++j)
                s_ += __expf(fmaf(acc[i][j][rg], -0.5f, cstr[j]) - m_);
            mx[sl] = m_; sm[sl] = s_;
        }

    #pragma unroll
    for (int d = 1; d < 16; d <<= 1) {
        #pragma unroll
        for (int sl = 0; sl < 16; ++sl) {
            const float pm = __shfl_xor(mx[sl], d, 64);
            const float ps = __shfl_xor(sm[sl], d, 64);
            const float nm = fmaxf(mx[sl], pm);
            sm[sl] = sm[sl] * __expf(mx[sl] - nm) + ps * __expf(pm - nm);
            mx[sl] = nm;
        }
    }

    if (wc == 0 && r == 0) {
        #pragma unroll
        for (int i = 0; i < 4; ++i)
            #pragma unroll
            for (int rg = 0; rg < 4; ++rg) {
                const int p2 = wr * 64 + i * 16 + kg * 4 + rg;
                lse_m[p2] = mx[i * 4 + rg];
                lse_d[p2] = sm[i * 4 + rg];
            }
    }
    __syncthreads();
    if (wc == 1 && r == 0) {
        const float thrv = thr[0];
        #pragma unroll
        for (int i = 0; i < 4; ++i)
            #pragma unroll
            for (int rg = 0; rg < 4; ++rg) {
                const int sl = i * 4 + rg;
                const int p2 = wr * 64 + i * 16 + kg * 4 + rg;
                const float om = lse_m[p2], os = lse_d[p2];
                const float nm = fmaxf(mx[sl], om);
                const float ss = sm[sl] * __expf(mx[sl] - nm) + os * __expf(om - nm);
                out[P0 + p2] = nm + __logf(ss) - 0.5f * nrm_s[p2] - thrv;
            }
    }
}

extern "C" void kernel_launch(void* const* d_in, const int* in_sizes, int n_in,
                              void* d_out, int out_size, void* d_ws, size_t ws_size,
                              hipStream_t stream)
{
    const float* X      = (const float*)d_in[0];
    const float* center = (const float*)d_in[1];
    const float* L      = (const float*)d_in[2];
    const float* weight = (const float*)d_in[3];
    const float* thr    = (const float*)d_in[4];
    float* out = (float*)d_out;

    // ws layout: cst [256] f32 | G [18*8192] bf16-as-short (~296 KB)
    float* cst = (float*)d_ws;
    short* G   = (short*)((char*)d_ws + 1024);

    gmm_prep<<<MCL, 256, 0, stream>>>(center, L, weight, G, cst);
    gmm_mfma<<<NPTS / BPTS, THREADS, 0, stream>>>(X, G, cst, thr, out);
}

// Round 9
// 110.088 us; speedup vs baseline: 3.5519x; 3.5519x over previous
//
#include <hip/hip_runtime.h>
#include <hip/hip_bf16.h>
#include <math.h>

#define NPTS 131072
#define DIM 32
#define MCL 256
#define NSTEP 18           // symmetric packing: 1 sq + 15 pair + 1 pair/lin + 1 lin/pad
#define BPTS 64            // points per block
#define THREADS 256

typedef __attribute__((ext_vector_type(8))) short s8v;    // 8 bf16 bit-patterns
typedef __attribute__((ext_vector_type(4))) short s4h;    // 4 bf16 (b64)
typedef __attribute__((ext_vector_type(4))) float f32x4;

__device__ __forceinline__ unsigned short f2bf(float f) {
    union { float f; unsigned u; } v; v.f = f;
    unsigned r = v.u + 0x7fffu + ((v.u >> 16) & 1u);   // RNE
    return (unsigned short)(r >> 16);
}

__device__ __forceinline__ void glds16(const void* g, void* l) {
    __builtin_amdgcn_global_load_lds(
        (const __attribute__((address_space(1))) unsigned int*)g,
        (__attribute__((address_space(3))) unsigned int*)l, 16, 0, 0);
}

// ---------------------------------------------------------------------------
// prep (256 threads/cluster): symmetric-packed G (bf16):
//  step 0           : c = E[k][k]                (squares; E = LL^T - I)
//  steps 1..15      : c = 2*E[k][(k+s)&31]       (pairs, circular diff s)
//  step 16, k<16    : c = 2*E[k][k+16]           (diff-16 pairs)
//  step 16, k>=16   : c = -2*Ac[k-16]            (linear)
//  step 17, k<16    : c = -2*Ac[k+16]            (linear)
//  step 17, k>=16   : c = 0                      (pad)
// G addr (shorts): s*8192 + (m>>4)*512 + (k>>3)*128 + (m&15)*8 + (k&7)
// logdet: register GE on wave 0 (col-per-lane, unrolled, no pivot).
// ---------------------------------------------------------------------------
__global__ __launch_bounds__(256) void gmm_prep(
    const float* __restrict__ center,
    const float* __restrict__ L,
    const float* __restrict__ weight,
    short* __restrict__ G,
    float* __restrict__ cst)
{
    const int m = blockIdx.x;
    const int t = threadIdx.x;
    __shared__ float Ls[DIM][DIM + 1];
    __shared__ float As[DIM][DIM + 1];
    __shared__ float Acs[DIM];
    __shared__ float red[DIM];

    const float* Lm = L + m * DIM * DIM;
    for (int k = t; k < DIM * DIM; k += 256)
        Ls[k >> 5][k & 31] = Lm[k];
    __syncthreads();

    // A = L L^T  (4 elems/thread)
    for (int idx = t; idx < DIM * DIM; idx += 256) {
        const int j = idx >> 5, l = idx & 31;
        float a = 0.f;
        #pragma unroll
        for (int d = 0; d < DIM; ++d) a = fmaf(Ls[j][d], Ls[l][d], a);
        As[j][l] = a;
    }
    __syncthreads();

    if (t < DIM) {
        float a = 0.f;
        #pragma unroll
        for (int l = 0; l < DIM; ++l) a = fmaf(As[t][l], center[m * DIM + l], a);
        Acs[t] = a;
        red[t] = a * center[m * DIM + t];
    }
    __syncthreads();

    const int mt = m >> 4, ml = m & 15;
    for (int idx = t; idx < NSTEP * 32; idx += 256) {
        const int s = idx >> 5, k = idx & 31;
        float c;
        if (s == 0)       c = As[k][k] - 1.0f;
        else if (s <= 15) c = 2.0f * As[k][(k + s) & 31];
        else if (s == 16) c = (k < 16) ? 2.0f * As[k][k + 16] : -2.0f * Acs[k - 16];
        else              c = (k < 16) ? -2.0f * Acs[k + 16] : 0.0f;
        G[s * 8192 + mt * 512 + (k >> 3) * 128 + ml * 8 + (k & 7)] = (short)f2bf(c);
    }

    if (t < 64) {
        // register GE, no pivot: lane j owns column j.
        float logdet = 0.f;
        if (t < DIM) {
            float col[DIM];
            #pragma unroll
            for (int r2 = 0; r2 < DIM; ++r2) col[r2] = Ls[r2][t];
            float prodabs = 1.0f;
            #pragma unroll
            for (int k = 0; k < DIM; ++k) {
                const float pv  = __shfl(col[k], k, 64);
                const float rpv = 1.0f / pv;
                const float cjk = col[k];
                #pragma unroll
                for (int t2 = k + 1; t2 < DIM; ++t2) {
                    const float f = __shfl(col[t2], k, 64) * rpv;
                    col[t2] = fmaf(-f, cjk, col[t2]);
                }
                prodabs *= fabsf(pv);
            }
            logdet = logf(prodabs);
        }

        float wsp = 0.f;
        for (int j = t; j < MCL; j += 64) wsp += fabsf(weight[j]);
        #pragma unroll
        for (int d2 = 1; d2 < 64; d2 <<= 1) wsp += __shfl_xor(wsp, d2, 64);

        if (t == 0) {
            float t3 = 0.f;
            #pragma unroll
            for (int j = 0; j < DIM; ++j) t3 += red[j];
            cst[m] = logf(fabsf(weight[m])) - logf(wsp) + logdet - 0.5f * t3;
        }
    }
}

// ---------------------------------------------------------------------------
// main kernel helpers: ALL element selection at compile time (R4/R8 lesson:
// no runtime-indexed arrays, and launch_bounds regs must cover acc+frags).
// ---------------------------------------------------------------------------
template<int OFF2, int E>
__device__ __forceinline__ float welem(const s4h a0, const s4h a1, const s4h a2) {
    constexpr int idx = OFF2 + E;
    unsigned short h;
    if constexpr (idx < 4)      h = (unsigned short)a0[idx & 3];
    else if constexpr (idx < 8) h = (unsigned short)a1[idx & 3];
    else                        h = (unsigned short)a2[idx & 3];
    return __uint_as_float(((unsigned)h) << 16);
}

template<int S, int E>
__device__ __forceinline__ float xsel(const float (&xkr)[8], int kg) {
    if constexpr (S == 16)      return (kg < 2) ? xkr[E] : 1.0f;
    else if constexpr (S == 17) return (kg < 2) ? 1.0f : 0.0f;
    else                        return xkr[E];
}

template<int S, int Q, int OFF2>
__device__ __forceinline__ unsigned mkpair(const float (&xkr)[8], int kg,
                                           const s4h a0, const s4h a1, const s4h a2) {
    const float p0 = xsel<S, 2 * Q>(xkr, kg)     * welem<OFF2, 2 * Q>(a0, a1, a2);
    const float p1 = xsel<S, 2 * Q + 1>(xkr, kg) * welem<OFF2, 2 * Q + 1>(a0, a1, a2);
    __hip_bfloat162 h2 = __float22bfloat162_rn(make_float2(p0, p1));
    return *reinterpret_cast<unsigned*>(&h2);
}

// ---------------------------------------------------------------------------
// main: block = 64 pts x 256 cl, 4 waves, WAVE TILE 64x64 (acc[4][4] = 64
// AGPRs -> total live ~150 regs -> fits 3 waves/SIMD at launch_bounds(256,3);
// R8's spill was acc[4][8]=128 under a 170-reg cap). Each wave owns a 64-col
// slice; A-gen duplicated across waves (VALU is not the bottleneck).
// 2-buffer B staging, issue-early, fused vmcnt(0)+barrier per step; 3
// independent blocks/CU de-synchronize the drains.
// ---------------------------------------------------------------------------
template<int S>
__device__ __forceinline__ void stage(const short* __restrict__ G,
                                      short (&Bb)[2][8192], int w, int lane)
{
    constexpr int b = S & 1;
    const short* gs = G + (size_t)S * 8192 + w * 2048 + lane * 8;
    #pragma unroll
    for (int q = 0; q < 4; ++q)
        glds16(gs + q * 512, &Bb[b][w * 2048 + q * 512]);
}

template<int S>
__device__ __forceinline__ void k_step(
    const short* __restrict__ G,
    short (&Bb)[2][8192],
    const short* __restrict__ Xh,
    const int (&rowh)[4],
    const float (&xk)[4][8],
    f32x4 (&acc)[4][4],
    int w, int lane, int kg)
{
    constexpr int cb = S & 1;
    // issue next-tile loads FIRST; they land under this step's VALU+MFMA
    if constexpr (S + 1 < NSTEP) stage<S + 1>(G, Bb, w, lane);

    constexpr int shv  = (S == 17) ? 16 : S;
    constexpr int off2 = shv & 3;
    const int bq = ((kg * 8 + shv) & 31) & ~3;   // aligned 4-half base

    s8v af[4];
    #pragma unroll
    for (int i = 0; i < 4; ++i) {
        const short* xr = Xh + rowh[i] + bq;
        const s4h a0 = *(const s4h*)(xr);
        const s4h a1 = *(const s4h*)(xr + 4);
        s4h a2 = a1;
        if constexpr (off2 != 0) a2 = *(const s4h*)(xr + 8);

        union { s8v v; unsigned u[4]; } U;
        U.u[0] = mkpair<S, 0, off2>(xk[i], kg, a0, a1, a2);
        U.u[1] = mkpair<S, 1, off2>(xk[i], kg, a0, a1, a2);
        U.u[2] = mkpair<S, 2, off2>(xk[i], kg, a0, a1, a2);
        U.u[3] = mkpair<S, 3, off2>(xk[i], kg, a0, a1, a2);
        af[i] = U.v;
    }

    s8v bf[4];
    #pragma unroll
    for (int j = 0; j < 4; ++j)
        bf[j] = *(const s8v*)&Bb[cb][(w * 4 + j) * 512 + lane * 8];
    #pragma unroll
    for (int i = 0; i < 4; ++i)
        #pragma unroll
        for (int j = 0; j < 4; ++j)
            acc[i][j] = __builtin_amdgcn_mfma_f32_16x16x32_bf16(
                af[i], bf[j], acc[i][j], 0, 0, 0);

    if constexpr (S + 1 < NSTEP)
        asm volatile("s_waitcnt vmcnt(0) lgkmcnt(0)\n\ts_barrier" ::: "memory");
}

template<int S>
__device__ __forceinline__ void k_loop(
    const short* __restrict__ G, short (&Bb)[2][8192],
    const short* __restrict__ Xh, const int (&rowh)[4],
    const float (&xk)[4][8], f32x4 (&acc)[4][4],
    int w, int lane, int kg)
{
    k_step<S>(G, Bb, Xh, rowh, xk, acc, w, lane, kg);
    if constexpr (S + 1 < NSTEP)
        k_loop<S + 1>(G, Bb, Xh, rowh, xk, acc, w, lane, kg);
}

__global__ __launch_bounds__(THREADS, 3) void gmm_mfma(
    const float* __restrict__ X,
    const short* __restrict__ G,
    const float* __restrict__ cstw,
    const float* __restrict__ thr,
    float* __restrict__ out)
{
    __shared__ __attribute__((aligned(16))) short Bb[2][8192];   // 32 KB
    __shared__ __attribute__((aligned(16))) short Xh[BPTS * 44]; // 5.5 KB
    __shared__ float nrm_s[BPTS];
    __shared__ float cst_s[MCL];
    __shared__ float lse_m[4][BPTS];
    __shared__ float lse_d[4][BPTS];

    const int tid  = threadIdx.x;
    const int lane = tid & 63;
    const int w    = tid >> 6;     // wave 0..3 = 64-col slice
    const int r    = lane & 15;
    const int kg   = lane >> 4;
    const int P0   = blockIdx.x * BPTS;

    // stage B[0] (async)
    stage<0>(G, Bb, w, lane);

    // resident f32 x-slices straight from global (same rows for all 4 waves)
    int rowh[4];
    float xk[4][8];
    #pragma unroll
    for (int i = 0; i < 4; ++i) {
        const int row = i * 16 + r;
        rowh[i] = row * 44;
        const float4* xg = reinterpret_cast<const float4*>(
            X + (size_t)(P0 + row) * DIM + kg * 8);
        const float4 a = xg[0], b = xg[1];
        xk[i][0] = a.x; xk[i][1] = a.y; xk[i][2] = a.z; xk[i][3] = a.w;
        xk[i][4] = b.x; xk[i][5] = b.y; xk[i][6] = b.z; xk[i][7] = b.w;
    }

    // stage Xh (bf16, +8 dup for circular wrap) + row norms: 64 rows by waves 0-1
    {
        const int p = tid >> 1, hf = tid & 1;
        if (tid < 128) {
            const float4* Xg = reinterpret_cast<const float4*>(
                X + (size_t)(P0 + p) * DIM + hf * 16);
            float part = 0.f;
            #pragma unroll
            for (int q = 0; q < 4; ++q) {
                const float4 v = Xg[q];
                const int kb = hf * 16 + 4 * q;
                Xh[p * 44 + kb + 0] = (short)f2bf(v.x);
                Xh[p * 44 + kb + 1] = (short)f2bf(v.y);
                Xh[p * 44 + kb + 2] = (short)f2bf(v.z);
                Xh[p * 44 + kb + 3] = (short)f2bf(v.w);
                if (!hf && q < 2) {
                    Xh[p * 44 + 32 + kb + 0] = (short)f2bf(v.x);
                    Xh[p * 44 + 32 + kb + 1] = (short)f2bf(v.y);
                    Xh[p * 44 + 32 + kb + 2] = (short)f2bf(v.z);
                    Xh[p * 44 + 32 + kb + 3] = (short)f2bf(v.w);
                }
                part = fmaf(v.x, v.x, part); part = fmaf(v.y, v.y, part);
                part = fmaf(v.z, v.z, part); part = fmaf(v.w, v.w, part);
            }
            part += __shfl_xor(part, 1, 64);
            if (!hf) nrm_s[p] = part;
        }
        cst_s[tid] = cstw[tid];
    }
    // Xh ds_writes drained + stage(0) landed; then everyone proceeds.
    asm volatile("s_waitcnt vmcnt(0) lgkmcnt(0)\n\ts_barrier" ::: "memory");

    f32x4 acc[4][4] = {};
    k_loop<0>(G, Bb, Xh, rowh, xk, acc, w, lane, kg);

    // ---- epilogue: weighted LSE over this wave's 64 clusters
    float cstr[4];
    #pragma unroll
    for (int j = 0; j < 4; ++j)
        cstr[j] = cst_s[w * 64 + j * 16 + r];

    float mx[16], sm[16];
    #pragma unroll
    for (int i = 0; i < 4; ++i)
        #pragma unroll
        for (int rg = 0; rg < 4; ++rg) {
            const int sl = i * 4 + rg;
            float m_ = -1e30f;
            #pragma unroll
            for (int j = 0; j < 4; ++j)
                m_ = fmaxf(m_, fmaf(acc[i][j][rg], -0.5f, cstr[j]));
            float s_ = 0.f;
            #pragma unroll
            for (int j = 0; j < 4; ++j)
                s_ += __expf(fmaf(acc[i][j][rg], -0.5f, cstr[j]) - m_);
            mx[sl] = m_; sm[sl] = s_;
        }

    // butterfly over the 16 col-lanes
    #pragma unroll
    for (int d = 1; d < 16; d <<= 1) {
        #pragma unroll
        for (int sl = 0; sl < 16; ++sl) {
            const float pm = __shfl_xor(mx[sl], d, 64);
            const float ps = __shfl_xor(sm[sl], d, 64);
            const float nm = fmaxf(mx[sl], pm);
            sm[sl] = sm[sl] * __expf(mx[sl] - nm) + ps * __expf(pm - nm);
            mx[sl] = nm;
        }
    }

    // per-wave partials -> LDS
    if (r == 0) {
        #pragma unroll
        for (int i = 0; i < 4; ++i)
            #pragma unroll
            for (int rg = 0; rg < 4; ++rg) {
                const int p2 = i * 16 + kg * 4 + rg;
                lse_m[w][p2] = mx[i * 4 + rg];
                lse_d[w][p2] = sm[i * 4 + rg];
            }
    }
    __syncthreads();

    // final merge of the 4 wave partials
    if (tid < BPTS) {
        float m = lse_m[0][tid], s = lse_d[0][tid];
        #pragma unroll
        for (int w2 = 1; w2 < 4; ++w2) {
            const float pm = lse_m[w2][tid], ps = lse_d[w2][tid];
            const float nm = fmaxf(m, pm);
            s = s * __expf(m - nm) + ps * __expf(pm - nm);
            m = nm;
        }
        out[P0 + tid] = m + __logf(s) - 0.5f * nrm_s[tid] - thr[0];
    }
}

extern "C" void kernel_launch(void* const* d_in, const int* in_sizes, int n_in,
                              void* d_out, int out_size, void* d_ws, size_t ws_size,
                              hipStream_t stream)
{
    const float* X      = (const float*)d_in[0];
    const float* center = (const float*)d_in[1];
    const float* L      = (const float*)d_in[2];
    const float* weight = (const float*)d_in[3];
    const float* thr    = (const float*)d_in[4];
    float* out = (float*)d_out;

    // ws layout: cst [256] f32 | G [18*8192] bf16-as-short (~296 KB)
    float* cst = (float*)d_ws;
    short* G   = (short*)((char*)d_ws + 1024);

    gmm_prep<<<MCL, 256, 0, stream>>>(center, L, weight, G, cst);
    gmm_mfma<<<NPTS / BPTS, THREADS, 0, stream>>>(X, G, cst, thr, out);
}

// Round 10
// 81.810 us; speedup vs baseline: 4.7797x; 1.3457x over previous
//
#include <hip/hip_runtime.h>
#include <hip/hip_bf16.h>
#include <math.h>

#define NPTS 131072
#define DIM 32
#define MCL 256
#define NSTEP 18           // symmetric packing: 1 sq + 15 pair + 1 pair/lin + 1 lin/pad
#define BPTS 64            // points per block
#define THREADS 256

typedef __attribute__((ext_vector_type(8))) short s8v;    // 8 bf16 bit-patterns
typedef __attribute__((ext_vector_type(4))) short s4h;    // 4 bf16 (b64)
typedef __attribute__((ext_vector_type(4))) float f32x4;

__device__ __forceinline__ unsigned short f2bf(float f) {
    union { float f; unsigned u; } v; v.f = f;
    unsigned r = v.u + 0x7fffu + ((v.u >> 16) & 1u);   // RNE
    return (unsigned short)(r >> 16);
}

__device__ __forceinline__ void glds16(const void* g, void* l) {
    __builtin_amdgcn_global_load_lds(
        (const __attribute__((address_space(1))) unsigned int*)g,
        (__attribute__((address_space(3))) unsigned int*)l, 16, 0, 0);
}

// ---------------------------------------------------------------------------
// prep (256 threads/cluster): symmetric-packed G (bf16):
//  step 0           : c = E[k][k]                (squares; E = LL^T - I)
//  steps 1..15      : c = 2*E[k][(k+s)&31]       (pairs, circular diff s)
//  step 16, k<16    : c = 2*E[k][k+16]           (diff-16 pairs)
//  step 16, k>=16   : c = -2*Ac[k-16]            (linear)
//  step 17, k<16    : c = -2*Ac[k+16]            (linear)
//  step 17, k>=16   : c = 0                      (pad)
// G addr (shorts): s*8192 + (m>>4)*512 + (k>>3)*128 + (m&15)*8 + (k&7)
// logdet: register GE on wave 0 (col-per-lane, unrolled, no pivot).
// ---------------------------------------------------------------------------
__global__ __launch_bounds__(256) void gmm_prep(
    const float* __restrict__ center,
    const float* __restrict__ L,
    const float* __restrict__ weight,
    short* __restrict__ G,
    float* __restrict__ cst)
{
    const int m = blockIdx.x;
    const int t = threadIdx.x;
    __shared__ float Ls[DIM][DIM + 1];
    __shared__ float As[DIM][DIM + 1];
    __shared__ float Acs[DIM];
    __shared__ float red[DIM];

    const float* Lm = L + m * DIM * DIM;
    for (int k = t; k < DIM * DIM; k += 256)
        Ls[k >> 5][k & 31] = Lm[k];
    __syncthreads();

    // A = L L^T  (4 elems/thread)
    for (int idx = t; idx < DIM * DIM; idx += 256) {
        const int j = idx >> 5, l = idx & 31;
        float a = 0.f;
        #pragma unroll
        for (int d = 0; d < DIM; ++d) a = fmaf(Ls[j][d], Ls[l][d], a);
        As[j][l] = a;
    }
    __syncthreads();

    if (t < DIM) {
        float a = 0.f;
        #pragma unroll
        for (int l = 0; l < DIM; ++l) a = fmaf(As[t][l], center[m * DIM + l], a);
        Acs[t] = a;
        red[t] = a * center[m * DIM + t];
    }
    __syncthreads();

    const int mt = m >> 4, ml = m & 15;
    for (int idx = t; idx < NSTEP * 32; idx += 256) {
        const int s = idx >> 5, k = idx & 31;
        float c;
        if (s == 0)       c = As[k][k] - 1.0f;
        else if (s <= 15) c = 2.0f * As[k][(k + s) & 31];
        else if (s == 16) c = (k < 16) ? 2.0f * As[k][k + 16] : -2.0f * Acs[k - 16];
        else              c = (k < 16) ? -2.0f * Acs[k + 16] : 0.0f;
        G[s * 8192 + mt * 512 + (k >> 3) * 128 + ml * 8 + (k & 7)] = (short)f2bf(c);
    }

    if (t < 64) {
        // register GE, no pivot: lane j owns column j.
        float logdet = 0.f;
        if (t < DIM) {
            float col[DIM];
            #pragma unroll
            for (int r2 = 0; r2 < DIM; ++r2) col[r2] = Ls[r2][t];
            float prodabs = 1.0f;
            #pragma unroll
            for (int k = 0; k < DIM; ++k) {
                const float pv  = __shfl(col[k], k, 64);
                const float rpv = 1.0f / pv;
                const float cjk = col[k];
                #pragma unroll
                for (int t2 = k + 1; t2 < DIM; ++t2) {
                    const float f = __shfl(col[t2], k, 64) * rpv;
                    col[t2] = fmaf(-f, cjk, col[t2]);
                }
                prodabs *= fabsf(pv);
            }
            logdet = logf(prodabs);
        }

        float wsp = 0.f;
        for (int j = t; j < MCL; j += 64) wsp += fabsf(weight[j]);
        #pragma unroll
        for (int d2 = 1; d2 < 64; d2 <<= 1) wsp += __shfl_xor(wsp, d2, 64);

        if (t == 0) {
            float t3 = 0.f;
            #pragma unroll
            for (int j = 0; j < DIM; ++j) t3 += red[j];
            cst[m] = logf(fabsf(weight[m])) - logf(wsp) + logdet - 0.5f * t3;
        }
    }
}

// ---------------------------------------------------------------------------
// main kernel helpers: ALL element selection at compile time (R4/R8 lesson).
// ---------------------------------------------------------------------------
template<int OFF2, int E>
__device__ __forceinline__ float welem(const s4h a0, const s4h a1, const s4h a2) {
    constexpr int idx = OFF2 + E;
    unsigned short h;
    if constexpr (idx < 4)      h = (unsigned short)a0[idx & 3];
    else if constexpr (idx < 8) h = (unsigned short)a1[idx & 3];
    else                        h = (unsigned short)a2[idx & 3];
    return __uint_as_float(((unsigned)h) << 16);
}

template<int S, int E>
__device__ __forceinline__ float xsel(const float (&xkr)[8], int kg) {
    if constexpr (S == 16)      return (kg < 2) ? xkr[E] : 1.0f;
    else if constexpr (S == 17) return (kg < 2) ? 1.0f : 0.0f;
    else                        return xkr[E];
}

template<int S, int Q, int OFF2>
__device__ __forceinline__ unsigned mkpair(const float (&xkr)[8], int kg,
                                           const s4h a0, const s4h a1, const s4h a2) {
    const float p0 = xsel<S, 2 * Q>(xkr, kg)     * welem<OFF2, 2 * Q>(a0, a1, a2);
    const float p1 = xsel<S, 2 * Q + 1>(xkr, kg) * welem<OFF2, 2 * Q + 1>(a0, a1, a2);
    __hip_bfloat162 h2 = __float22bfloat162_rn(make_float2(p0, p1));
    return *reinterpret_cast<unsigned*>(&h2);
}

// ---------------------------------------------------------------------------
// main: block = 64 pts x 256 cl, 4 waves, WAVE TILE 32x128: acc[2][8]=64 AGPR
// (fits 3 waves/SIMD under launch_bounds(256,3)) with only 2 A-fragments/step
// feeding 16 MFMAs -- same MFMA:A-gen ratio as R6 (R9's 64x64 tile doubled
// the VALU share and lost). wr = row half (32 pts), wc = col half (128 cl).
// 2-buffer B staging, issue-early, fused vmcnt(0)+barrier per step; 3
// blocks/CU de-synchronize the drains.
// ---------------------------------------------------------------------------
template<int S>
__device__ __forceinline__ void stage(const short* __restrict__ G,
                                      short (&Bb)[2][8192], int w, int lane)
{
    constexpr int b = S & 1;
    const short* gs = G + (size_t)S * 8192 + w * 2048 + lane * 8;
    #pragma unroll
    for (int q = 0; q < 4; ++q)
        glds16(gs + q * 512, &Bb[b][w * 2048 + q * 512]);
}

template<int S>
__device__ __forceinline__ void k_step(
    const short* __restrict__ G,
    short (&Bb)[2][8192],
    const short* __restrict__ Xh,
    const int (&rowh)[2],
    const float (&xk)[2][8],
    f32x4 (&acc)[2][8],
    int w, int lane, int kg, int wc)
{
    constexpr int cb = S & 1;
    // issue next-tile loads FIRST; they land under this step's VALU+MFMA
    if constexpr (S + 1 < NSTEP) stage<S + 1>(G, Bb, w, lane);

    constexpr int shv  = (S == 17) ? 16 : S;
    constexpr int off2 = shv & 3;
    const int bq = ((kg * 8 + shv) & 31) & ~3;   // aligned 4-half base

    s8v af[2];
    #pragma unroll
    for (int i = 0; i < 2; ++i) {
        const short* xr = Xh + rowh[i] + bq;
        const s4h a0 = *(const s4h*)(xr);
        const s4h a1 = *(const s4h*)(xr + 4);
        s4h a2 = a1;
        if constexpr (off2 != 0) a2 = *(const s4h*)(xr + 8);

        union { s8v v; unsigned u[4]; } U;
        U.u[0] = mkpair<S, 0, off2>(xk[i], kg, a0, a1, a2);
        U.u[1] = mkpair<S, 1, off2>(xk[i], kg, a0, a1, a2);
        U.u[2] = mkpair<S, 2, off2>(xk[i], kg, a0, a1, a2);
        U.u[3] = mkpair<S, 3, off2>(xk[i], kg, a0, a1, a2);
        af[i] = U.v;
    }

    s8v bf[8];
    #pragma unroll
    for (int j = 0; j < 8; ++j)
        bf[j] = *(const s8v*)&Bb[cb][(wc * 8 + j) * 512 + lane * 8];
    #pragma unroll
    for (int i = 0; i < 2; ++i)
        #pragma unroll
        for (int j = 0; j < 8; ++j)
            acc[i][j] = __builtin_amdgcn_mfma_f32_16x16x32_bf16(
                af[i], bf[j], acc[i][j], 0, 0, 0);

    if constexpr (S + 1 < NSTEP)
        asm volatile("s_waitcnt vmcnt(0) lgkmcnt(0)\n\ts_barrier" ::: "memory");
}

template<int S>
__device__ __forceinline__ void k_loop(
    const short* __restrict__ G, short (&Bb)[2][8192],
    const short* __restrict__ Xh, const int (&rowh)[2],
    const float (&xk)[2][8], f32x4 (&acc)[2][8],
    int w, int lane, int kg, int wc)
{
    k_step<S>(G, Bb, Xh, rowh, xk, acc, w, lane, kg, wc);
    if constexpr (S + 1 < NSTEP)
        k_loop<S + 1>(G, Bb, Xh, rowh, xk, acc, w, lane, kg, wc);
}

__global__ __launch_bounds__(THREADS, 3) void gmm_mfma(
    const float* __restrict__ X,
    const short* __restrict__ G,
    const float* __restrict__ cstw,
    const float* __restrict__ thr,
    float* __restrict__ out)
{
    __shared__ __attribute__((aligned(16))) short Bb[2][8192];   // 32 KB
    __shared__ __attribute__((aligned(16))) short Xh[BPTS * 44]; // 5.5 KB
    __shared__ float nrm_s[BPTS];
    __shared__ float cst_s[MCL];
    __shared__ float lse_m[BPTS];
    __shared__ float lse_d[BPTS];

    const int tid  = threadIdx.x;
    const int lane = tid & 63;
    const int w    = tid >> 6;     // wave 0..3
    const int wr   = w & 1;        // row half: 32 points
    const int wc   = w >> 1;       // col half: 128 clusters
    const int r    = lane & 15;
    const int kg   = lane >> 4;
    const int P0   = blockIdx.x * BPTS;

    // stage B[0] (async)
    stage<0>(G, Bb, w, lane);

    // resident f32 x-slices straight from global (block's X slice is cache-hot)
    int rowh[2];
    float xk[2][8];
    #pragma unroll
    for (int i = 0; i < 2; ++i) {
        const int row = wr * 32 + i * 16 + r;
        rowh[i] = row * 44;
        const float4* xg = reinterpret_cast<const float4*>(
            X + (size_t)(P0 + row) * DIM + kg * 8);
        const float4 a = xg[0], b = xg[1];
        xk[i][0] = a.x; xk[i][1] = a.y; xk[i][2] = a.z; xk[i][3] = a.w;
        xk[i][4] = b.x; xk[i][5] = b.y; xk[i][6] = b.z; xk[i][7] = b.w;
    }

    // stage Xh (bf16, +8 dup for circular wrap) + row norms (64 rows, tid<128)
    {
        const int p = tid >> 1, hf = tid & 1;
        if (tid < 128) {
            const float4* Xg = reinterpret_cast<const float4*>(
                X + (size_t)(P0 + p) * DIM + hf * 16);
            float part = 0.f;
            #pragma unroll
            for (int q = 0; q < 4; ++q) {
                const float4 v = Xg[q];
                const int kb = hf * 16 + 4 * q;
                Xh[p * 44 + kb + 0] = (short)f2bf(v.x);
                Xh[p * 44 + kb + 1] = (short)f2bf(v.y);
                Xh[p * 44 + kb + 2] = (short)f2bf(v.z);
                Xh[p * 44 + kb + 3] = (short)f2bf(v.w);
                if (!hf && q < 2) {
                    Xh[p * 44 + 32 + kb + 0] = (short)f2bf(v.x);
                    Xh[p * 44 + 32 + kb + 1] = (short)f2bf(v.y);
                    Xh[p * 44 + 32 + kb + 2] = (short)f2bf(v.z);
                    Xh[p * 44 + 32 + kb + 3] = (short)f2bf(v.w);
                }
                part = fmaf(v.x, v.x, part); part = fmaf(v.y, v.y, part);
                part = fmaf(v.z, v.z, part); part = fmaf(v.w, v.w, part);
            }
            part += __shfl_xor(part, 1, 64);
            if (!hf) nrm_s[p] = part;
        }
        cst_s[tid] = cstw[tid];
    }
    // Xh ds_writes drained + stage(0) landed; then everyone proceeds.
    asm volatile("s_waitcnt vmcnt(0) lgkmcnt(0)\n\ts_barrier" ::: "memory");

    f32x4 acc[2][8] = {};
    k_loop<0>(G, Bb, Xh, rowh, xk, acc, w, lane, kg, wc);

    // ---- epilogue: weighted LSE over this wave's 128 clusters
    float cstr[8];
    #pragma unroll
    for (int j = 0; j < 8; ++j)
        cstr[j] = cst_s[wc * 128 + j * 16 + r];

    float mx[8], sm[8];
    #pragma unroll
    for (int i = 0; i < 2; ++i)
        #pragma unroll
        for (int rg = 0; rg < 4; ++rg) {
            const int sl = i * 4 + rg;
            float m_ = -1e30f;
            #pragma unroll
            for (int j = 0; j < 8; ++j)
                m_ = fmaxf(m_, fmaf(acc[i][j][rg], -0.5f, cstr[j]));
            float s_ = 0.f;
            #pragma unroll
            for (int j = 0; j < 8; ++j)
                s_ += __expf(fmaf(acc[i][j][rg], -0.5f, cstr[j]) - m_);
            mx[sl] = m_; sm[sl] = s_;
        }

    // butterfly over the 16 col-lanes
    #pragma unroll
    for (int d = 1; d < 16; d <<= 1) {
        #pragma unroll
        for (int sl = 0; sl < 8; ++sl) {
            const float pm = __shfl_xor(mx[sl], d, 64);
            const float ps = __shfl_xor(sm[sl], d, 64);
            const float nm = fmaxf(mx[sl], pm);
            sm[sl] = sm[sl] * __expf(mx[sl] - nm) + ps * __expf(pm - nm);
            mx[sl] = nm;
        }
    }

    // cross col-half merge via LDS
    if (wc == 0 && r == 0) {
        #pragma unroll
        for (int i = 0; i < 2; ++i)
            #pragma unroll
            for (int rg = 0; rg < 4; ++rg) {
                const int p2 = wr * 32 + i * 16 + kg * 4 + rg;
                lse_m[p2] = mx[i * 4 + rg];
                lse_d[p2] = sm[i * 4 + rg];
            }
    }
    __syncthreads();
    if (wc == 1 && r == 0) {
        const float thrv = thr[0];
        #pragma unroll
        for (int i = 0; i < 2; ++i)
            #pragma unroll
            for (int rg = 0; rg < 4; ++rg) {
                const int sl = i * 4 + rg;
                const int p2 = wr * 32 + i * 16 + kg * 4 + rg;
                const float om = lse_m[p2], os = lse_d[p2];
                const float nm = fmaxf(mx[sl], om);
                const float ss = sm[sl] * __expf(mx[sl] - nm) + os * __expf(om - nm);
                out[P0 + p2] = nm + __logf(ss) - 0.5f * nrm_s[p2] - thrv;
            }
    }
}

extern "C" void kernel_launch(void* const* d_in, const int* in_sizes, int n_in,
                              void* d_out, int out_size, void* d_ws, size_t ws_size,
                              hipStream_t stream)
{
    const float* X      = (const float*)d_in[0];
    const float* center = (const float*)d_in[1];
    const float* L      = (const float*)d_in[2];
    const float* weight = (const float*)d_in[3];
    const float* thr    = (const float*)d_in[4];
    float* out = (float*)d_out;

    // ws layout: cst [256] f32 | G [18*8192] bf16-as-short (~296 KB)
    float* cst = (float*)d_ws;
    short* G   = (short*)((char*)d_ws + 1024);

    gmm_prep<<<MCL, 256, 0, stream>>>(center, L, weight, G, cst);
    gmm_mfma<<<NPTS / BPTS, THREADS, 0, stream>>>(X, G, cst, thr, out);
}

// Round 11
// 75.016 us; speedup vs baseline: 5.2125x; 1.0906x over previous
//
#include <hip/hip_runtime.h>
#include <hip/hip_bf16.h>
#include <math.h>

#define NPTS 131072
#define DIM 32
#define MCL 256
#define NSTEP 18           // symmetric packing: 1 sq + 15 pair + 1 pair/lin + 1 lin/pad
#define BPTS 64            // points per block
#define THREADS 256

typedef __attribute__((ext_vector_type(8))) short s8v;    // 8 bf16 bit-patterns
typedef __attribute__((ext_vector_type(4))) short s4h;    // 4 bf16 (b64)
typedef __attribute__((ext_vector_type(4))) float f32x4;

__device__ __forceinline__ unsigned short f2bf(float f) {
    union { float f; unsigned u; } v; v.f = f;
    unsigned r = v.u + 0x7fffu + ((v.u >> 16) & 1u);   // RNE
    return (unsigned short)(r >> 16);
}

// ---------------------------------------------------------------------------
// prep (256 threads/cluster): symmetric-packed G (bf16):
//  step 0           : c = E[k][k]                (squares; E = LL^T - I)
//  steps 1..15      : c = 2*E[k][(k+s)&31]       (pairs, circular diff s)
//  step 16, k<16    : c = 2*E[k][k+16]           (diff-16 pairs)
//  step 16, k>=16   : c = -2*Ac[k-16]            (linear)
//  step 17, k<16    : c = -2*Ac[k+16]            (linear)
//  step 17, k>=16   : c = 0                      (pad)
// G addr (shorts): s*8192 + (m>>4)*512 + (k>>3)*128 + (m&15)*8 + (k&7)
// logdet: register GE on wave 0 (col-per-lane, unrolled, no pivot).
// ---------------------------------------------------------------------------
__global__ __launch_bounds__(256) void gmm_prep(
    const float* __restrict__ center,
    const float* __restrict__ L,
    const float* __restrict__ weight,
    short* __restrict__ G,
    float* __restrict__ cst)
{
    const int m = blockIdx.x;
    const int t = threadIdx.x;
    __shared__ float Ls[DIM][DIM + 1];
    __shared__ float As[DIM][DIM + 1];
    __shared__ float Acs[DIM];
    __shared__ float red[DIM];

    const float* Lm = L + m * DIM * DIM;
    for (int k = t; k < DIM * DIM; k += 256)
        Ls[k >> 5][k & 31] = Lm[k];
    __syncthreads();

    // A = L L^T  (4 elems/thread)
    for (int idx = t; idx < DIM * DIM; idx += 256) {
        const int j = idx >> 5, l = idx & 31;
        float a = 0.f;
        #pragma unroll
        for (int d = 0; d < DIM; ++d) a = fmaf(Ls[j][d], Ls[l][d], a);
        As[j][l] = a;
    }
    __syncthreads();

    if (t < DIM) {
        float a = 0.f;
        #pragma unroll
        for (int l = 0; l < DIM; ++l) a = fmaf(As[t][l], center[m * DIM + l], a);
        Acs[t] = a;
        red[t] = a * center[m * DIM + t];
    }
    __syncthreads();

    const int mt = m >> 4, ml = m & 15;
    for (int idx = t; idx < NSTEP * 32; idx += 256) {
        const int s = idx >> 5, k = idx & 31;
        float c;
        if (s == 0)       c = As[k][k] - 1.0f;
        else if (s <= 15) c = 2.0f * As[k][(k + s) & 31];
        else if (s == 16) c = (k < 16) ? 2.0f * As[k][k + 16] : -2.0f * Acs[k - 16];
        else              c = (k < 16) ? -2.0f * Acs[k + 16] : 0.0f;
        G[s * 8192 + mt * 512 + (k >> 3) * 128 + ml * 8 + (k & 7)] = (short)f2bf(c);
    }

    if (t < 64) {
        // register GE, no pivot: lane j owns column j.
        float logdet = 0.f;
        if (t < DIM) {
            float col[DIM];
            #pragma unroll
            for (int r2 = 0; r2 < DIM; ++r2) col[r2] = Ls[r2][t];
            float prodabs = 1.0f;
            #pragma unroll
            for (int k = 0; k < DIM; ++k) {
                const float pv  = __shfl(col[k], k, 64);
                const float rpv = 1.0f / pv;
                const float cjk = col[k];
                #pragma unroll
                for (int t2 = k + 1; t2 < DIM; ++t2) {
                    const float f = __shfl(col[t2], k, 64) * rpv;
                    col[t2] = fmaf(-f, cjk, col[t2]);
                }
                prodabs *= fabsf(pv);
            }
            logdet = logf(prodabs);
        }

        float wsp = 0.f;
        for (int j = t; j < MCL; j += 64) wsp += fabsf(weight[j]);
        #pragma unroll
        for (int d2 = 1; d2 < 64; d2 <<= 1) wsp += __shfl_xor(wsp, d2, 64);

        if (t == 0) {
            float t3 = 0.f;
            #pragma unroll
            for (int j = 0; j < DIM; ++j) t3 += red[j];
            cst[m] = logf(fabsf(weight[m])) - logf(wsp) + logdet - 0.5f * t3;
        }
    }
}

// ---------------------------------------------------------------------------
// main kernel helpers: ALL element selection at compile time (R4/R8 lesson).
// ---------------------------------------------------------------------------
template<int OFF2, int E>
__device__ __forceinline__ float welem(const s4h a0, const s4h a1, const s4h a2) {
    constexpr int idx = OFF2 + E;
    unsigned short h;
    if constexpr (idx < 4)      h = (unsigned short)a0[idx & 3];
    else if constexpr (idx < 8) h = (unsigned short)a1[idx & 3];
    else                        h = (unsigned short)a2[idx & 3];
    return __uint_as_float(((unsigned)h) << 16);
}

template<int S, int E>
__device__ __forceinline__ float xsel(const float (&xkr)[8], int kg) {
    if constexpr (S == 16)      return (kg < 2) ? xkr[E] : 1.0f;
    else if constexpr (S == 17) return (kg < 2) ? 1.0f : 0.0f;
    else                        return xkr[E];
}

template<int S, int Q, int OFF2>
__device__ __forceinline__ unsigned mkpair(const float (&xkr)[8], int kg,
                                           const s4h a0, const s4h a1, const s4h a2) {
    const float p0 = xsel<S, 2 * Q>(xkr, kg)     * welem<OFF2, 2 * Q>(a0, a1, a2);
    const float p1 = xsel<S, 2 * Q + 1>(xkr, kg) * welem<OFF2, 2 * Q + 1>(a0, a1, a2);
    __hip_bfloat162 h2 = __float22bfloat162_rn(make_float2(p0, p1));
    return *reinterpret_cast<unsigned*>(&h2);
}

// ---------------------------------------------------------------------------
// main: block = 64 pts x 256 cl, 4 waves, wave tile 32x128, acc[2][8]=64 AGPR.
// NO LDS staging for B and NO K-loop barriers: B fragments are loaded
// straight from G into registers (G = 296 KB, L1/L2-resident; coalesced
// 1 KB/instr; SGPR base + imm offsets). Single-buffer bf with issue-after-use:
// step S = {af-gen(S) from LDS Xh} {16 MFMA on bf} {load bf <- step S+1}
// {sched_barrier}. WAR on bf keeps order; sched_barrier(0) stops cross-step
// hoisting (R7's spill). Waves free-run; 3 blocks/CU desynchronized.
// ---------------------------------------------------------------------------
template<int S>
__device__ __forceinline__ void k_step(
    const short* __restrict__ gw,      // G + wc*4096 + lane*8 (shorts)
    const short* __restrict__ Xh,
    const int (&rowh)[2],
    const float (&xk)[2][8],
    s8v (&bf)[8],
    f32x4 (&acc)[2][8],
    int kg)
{
    constexpr int shv  = (S == 17) ? 16 : S;
    constexpr int off2 = shv & 3;
    const int bq = ((kg * 8 + shv) & 31) & ~3;   // aligned 4-half base

    s8v af[2];
    #pragma unroll
    for (int i = 0; i < 2; ++i) {
        const short* xr = Xh + rowh[i] + bq;
        const s4h a0 = *(const s4h*)(xr);
        const s4h a1 = *(const s4h*)(xr + 4);
        s4h a2 = a1;
        if constexpr (off2 != 0) a2 = *(const s4h*)(xr + 8);

        union { s8v v; unsigned u[4]; } U;
        U.u[0] = mkpair<S, 0, off2>(xk[i], kg, a0, a1, a2);
        U.u[1] = mkpair<S, 1, off2>(xk[i], kg, a0, a1, a2);
        U.u[2] = mkpair<S, 2, off2>(xk[i], kg, a0, a1, a2);
        U.u[3] = mkpair<S, 3, off2>(xk[i], kg, a0, a1, a2);
        af[i] = U.v;
    }

    #pragma unroll
    for (int i = 0; i < 2; ++i)
        #pragma unroll
        for (int j = 0; j < 8; ++j)
            acc[i][j] = __builtin_amdgcn_mfma_f32_16x16x32_bf16(
                af[i], bf[j], acc[i][j], 0, 0, 0);

    // bf now dead -> refill with next step's fragments (L1/L2-hot global)
    if constexpr (S + 1 < NSTEP) {
        #pragma unroll
        for (int j = 0; j < 8; ++j)
            bf[j] = *(const s8v*)(gw + (size_t)(S + 1) * 8192 + j * 512);
    }
    __builtin_amdgcn_sched_barrier(0);   // keep step regions separate (R7 lesson)
}

template<int S>
__device__ __forceinline__ void k_loop(
    const short* __restrict__ gw, const short* __restrict__ Xh,
    const int (&rowh)[2], const float (&xk)[2][8],
    s8v (&bf)[8], f32x4 (&acc)[2][8], int kg)
{
    k_step<S>(gw, Xh, rowh, xk, bf, acc, kg);
    if constexpr (S + 1 < NSTEP)
        k_loop<S + 1>(gw, Xh, rowh, xk, bf, acc, kg);
}

__global__ __launch_bounds__(THREADS, 3) void gmm_mfma(
    const float* __restrict__ X,
    const short* __restrict__ G,
    const float* __restrict__ cstw,
    const float* __restrict__ thr,
    float* __restrict__ out)
{
    __shared__ __attribute__((aligned(16))) short Xh[BPTS * 44]; // 5.5 KB
    __shared__ float nrm_s[BPTS];
    __shared__ float cst_s[MCL];
    __shared__ float lse_m[BPTS];
    __shared__ float lse_d[BPTS];

    const int tid  = threadIdx.x;
    const int lane = tid & 63;
    const int w    = tid >> 6;     // wave 0..3
    const int wr   = w & 1;        // row half: 32 points
    const int wc   = w >> 1;       // col half: 128 clusters
    const int r    = lane & 15;
    const int kg   = lane >> 4;
    const int P0   = blockIdx.x * BPTS;

    // per-wave B pointer: cols wc*128.., this lane's 8 shorts
    const short* gw = G + wc * 4096 + lane * 8;

    // resident f32 x-slices straight from global (block's X slice is cache-hot)
    int rowh[2];
    float xk[2][8];
    #pragma unroll
    for (int i = 0; i < 2; ++i) {
        const int row = wr * 32 + i * 16 + r;
        rowh[i] = row * 44;
        const float4* xg = reinterpret_cast<const float4*>(
            X + (size_t)(P0 + row) * DIM + kg * 8);
        const float4 a = xg[0], b = xg[1];
        xk[i][0] = a.x; xk[i][1] = a.y; xk[i][2] = a.z; xk[i][3] = a.w;
        xk[i][4] = b.x; xk[i][5] = b.y; xk[i][6] = b.z; xk[i][7] = b.w;
    }

    // stage Xh (bf16, +8 dup for circular wrap) + row norms (64 rows, tid<128)
    {
        const int p = tid >> 1, hf = tid & 1;
        if (tid < 128) {
            const float4* Xg = reinterpret_cast<const float4*>(
                X + (size_t)(P0 + p) * DIM + hf * 16);
            float part = 0.f;
            #pragma unroll
            for (int q = 0; q < 4; ++q) {
                const float4 v = Xg[q];
                const int kb = hf * 16 + 4 * q;
                Xh[p * 44 + kb + 0] = (short)f2bf(v.x);
                Xh[p * 44 + kb + 1] = (short)f2bf(v.y);
                Xh[p * 44 + kb + 2] = (short)f2bf(v.z);
                Xh[p * 44 + kb + 3] = (short)f2bf(v.w);
                if (!hf && q < 2) {
                    Xh[p * 44 + 32 + kb + 0] = (short)f2bf(v.x);
                    Xh[p * 44 + 32 + kb + 1] = (short)f2bf(v.y);
                    Xh[p * 44 + 32 + kb + 2] = (short)f2bf(v.z);
                    Xh[p * 44 + 32 + kb + 3] = (short)f2bf(v.w);
                }
                part = fmaf(v.x, v.x, part); part = fmaf(v.y, v.y, part);
                part = fmaf(v.z, v.z, part); part = fmaf(v.w, v.w, part);
            }
            part += __shfl_xor(part, 1, 64);
            if (!hf) nrm_s[p] = part;
        }
        cst_s[tid] = cstw[tid];
    }

    // prologue: load step-0 B fragments into registers
    s8v bf[8];
    #pragma unroll
    for (int j = 0; j < 8; ++j)
        bf[j] = *(const s8v*)(gw + j * 512);

    __syncthreads();   // Xh/nrm/cst visible to all waves

    f32x4 acc[2][8] = {};
    k_loop<0>(gw, Xh, rowh, xk, bf, acc, kg);

    // ---- epilogue: weighted LSE over this wave's 128 clusters
    float cstr[8];
    #pragma unroll
    for (int j = 0; j < 8; ++j)
        cstr[j] = cst_s[wc * 128 + j * 16 + r];

    float mx[8], sm[8];
    #pragma unroll
    for (int i = 0; i < 2; ++i)
        #pragma unroll
        for (int rg = 0; rg < 4; ++rg) {
            const int sl = i * 4 + rg;
            float m_ = -1e30f;
            #pragma unroll
            for (int j = 0; j < 8; ++j)
                m_ = fmaxf(m_, fmaf(acc[i][j][rg], -0.5f, cstr[j]));
            float s_ = 0.f;
            #pragma unroll
            for (int j = 0; j < 8; ++j)
                s_ += __expf(fmaf(acc[i][j][rg], -0.5f, cstr[j]) - m_);
            mx[sl] = m_; sm[sl] = s_;
        }

    // butterfly over the 16 col-lanes
    #pragma unroll
    for (int d = 1; d < 16; d <<= 1) {
        #pragma unroll
        for (int sl = 0; sl < 8; ++sl) {
            const float pm = __shfl_xor(mx[sl], d, 64);
            const float ps = __shfl_xor(sm[sl], d, 64);
            const float nm = fmaxf(mx[sl], pm);
            sm[sl] = sm[sl] * __expf(mx[sl] - nm) + ps * __expf(pm - nm);
            mx[sl] = nm;
        }
    }

    // cross col-half merge via LDS
    if (wc == 0 && r == 0) {
        #pragma unroll
        for (int i = 0; i < 2; ++i)
            #pragma unroll
            for (int rg = 0; rg < 4; ++rg) {
                const int p2 = wr * 32 + i * 16 + kg * 4 + rg;
                lse_m[p2] = mx[i * 4 + rg];
                lse_d[p2] = sm[i * 4 + rg];
            }
    }
    __syncthreads();
    if (wc == 1 && r == 0) {
        const float thrv = thr[0];
        #pragma unroll
        for (int i = 0; i < 2; ++i)
            #pragma unroll
            for (int rg = 0; rg < 4; ++rg) {
                const int sl = i * 4 + rg;
                const int p2 = wr * 32 + i * 16 + kg * 4 + rg;
                const float om = lse_m[p2], os = lse_d[p2];
                const float nm = fmaxf(mx[sl], om);
                const float ss = sm[sl] * __expf(mx[sl] - nm) + os * __expf(om - nm);
                out[P0 + p2] = nm + __logf(ss) - 0.5f * nrm_s[p2] - thrv;
            }
    }
}

extern "C" void kernel_launch(void* const* d_in, const int* in_sizes, int n_in,
                              void* d_out, int out_size, void* d_ws, size_t ws_size,
                              hipStream_t stream)
{
    const float* X      = (const float*)d_in[0];
    const float* center = (const float*)d_in[1];
    const float* L      = (const float*)d_in[2];
    const float* weight = (const float*)d_in[3];
    const float* thr    = (const float*)d_in[4];
    float* out = (float*)d_out;

    // ws layout: cst [256] f32 | G [18*8192] bf16-as-short (~296 KB)
    float* cst = (float*)d_ws;
    short* G   = (short*)((char*)d_ws + 1024);

    gmm_prep<<<MCL, 256, 0, stream>>>(center, L, weight, G, cst);
    gmm_mfma<<<NPTS / BPTS, THREADS, 0, stream>>>(X, G, cst, thr, out);
}

// Round 12
// 68.796 us; speedup vs baseline: 5.6838x; 1.0904x over previous
//
#include <hip/hip_runtime.h>
#include <hip/hip_bf16.h>
#include <math.h>

#define NPTS 131072
#define DIM 32
#define MCL 256
#define NSTEP 18           // symmetric packing: 1 sq + 15 pair + 1 pair/lin + 1 lin/pad
#define BPTS 64            // points per block
#define THREADS 256

typedef __attribute__((ext_vector_type(8))) _Float16 f16x8;   // MFMA A/B fragment
typedef __attribute__((ext_vector_type(2))) _Float16 h2v;     // packed f16 pair
typedef __attribute__((ext_vector_type(2))) unsigned u2v;     // 2 dwords (4 f16)
typedef __attribute__((ext_vector_type(4))) float f32x4;

__device__ __forceinline__ short f2h(float f) {
    _Float16 h = (_Float16)f;
    union { _Float16 h; short s; } X; X.h = h; return X.s;
}

// ---------------------------------------------------------------------------
// prep (256 threads/cluster): symmetric-packed G (f16):
//  step 0           : c = E[k][k]                (squares; E = LL^T - I)
//  steps 1..15      : c = 2*E[k][(k+s)&31]       (pairs, circular diff s)
//  step 16, k<16    : c = 2*E[k][k+16]           (diff-16 pairs)
//  step 16, k>=16   : c = -2*Ac[k-16]            (linear; A-side = x[k-16])
//  step 17, k<16    : c = -2*Ac[k+16]            (linear; A-side = x[k+16])
//  step 17, k>=16   : c = 0                      (pad)
// G addr (shorts): s*8192 + (m>>4)*512 + (k>>3)*128 + (m&15)*8 + (k&7)
// logdet: register GE on wave 0 (col-per-lane, unrolled, no pivot).
// ---------------------------------------------------------------------------
__global__ __launch_bounds__(256) void gmm_prep(
    const float* __restrict__ center,
    const float* __restrict__ L,
    const float* __restrict__ weight,
    short* __restrict__ G,
    float* __restrict__ cst)
{
    const int m = blockIdx.x;
    const int t = threadIdx.x;
    __shared__ float Ls[DIM][DIM + 1];
    __shared__ float As[DIM][DIM + 1];
    __shared__ float Acs[DIM];
    __shared__ float red[DIM];

    const float* Lm = L + m * DIM * DIM;
    for (int k = t; k < DIM * DIM; k += 256)
        Ls[k >> 5][k & 31] = Lm[k];
    __syncthreads();

    // A = L L^T  (4 elems/thread)
    for (int idx = t; idx < DIM * DIM; idx += 256) {
        const int j = idx >> 5, l = idx & 31;
        float a = 0.f;
        #pragma unroll
        for (int d = 0; d < DIM; ++d) a = fmaf(Ls[j][d], Ls[l][d], a);
        As[j][l] = a;
    }
    __syncthreads();

    if (t < DIM) {
        float a = 0.f;
        #pragma unroll
        for (int l = 0; l < DIM; ++l) a = fmaf(As[t][l], center[m * DIM + l], a);
        Acs[t] = a;
        red[t] = a * center[m * DIM + t];
    }
    __syncthreads();

    const int mt = m >> 4, ml = m & 15;
    for (int idx = t; idx < NSTEP * 32; idx += 256) {
        const int s = idx >> 5, k = idx & 31;
        float c;
        if (s == 0)       c = As[k][k] - 1.0f;
        else if (s <= 15) c = 2.0f * As[k][(k + s) & 31];
        else if (s == 16) c = (k < 16) ? 2.0f * As[k][k + 16] : -2.0f * Acs[k - 16];
        else              c = (k < 16) ? -2.0f * Acs[k + 16] : 0.0f;
        G[s * 8192 + mt * 512 + (k >> 3) * 128 + ml * 8 + (k & 7)] = f2h(c);
    }

    if (t < 64) {
        // register GE, no pivot: lane j owns column j.
        float logdet = 0.f;
        if (t < DIM) {
            float col[DIM];
            #pragma unroll
            for (int r2 = 0; r2 < DIM; ++r2) col[r2] = Ls[r2][t];
            float prodabs = 1.0f;
            #pragma unroll
            for (int k = 0; k < DIM; ++k) {
                const float pv  = __shfl(col[k], k, 64);
                const float rpv = 1.0f / pv;
                const float cjk = col[k];
                #pragma unroll
                for (int t2 = k + 1; t2 < DIM; ++t2) {
                    const float f = __shfl(col[t2], k, 64) * rpv;
                    col[t2] = fmaf(-f, cjk, col[t2]);
                }
                prodabs *= fabsf(pv);
            }
            logdet = logf(prodabs);
        }

        float wsp = 0.f;
        for (int j = t; j < MCL; j += 64) wsp += fabsf(weight[j]);
        #pragma unroll
        for (int d2 = 1; d2 < 64; d2 <<= 1) wsp += __shfl_xor(wsp, d2, 64);

        if (t == 0) {
            float t3 = 0.f;
            #pragma unroll
            for (int j = 0; j < DIM; ++j) t3 += red[j];
            cst[m] = logf(fabsf(weight[m])) - logf(wsp) + logdet - 0.5f * t3;
        }
    }
}

// ---------------------------------------------------------------------------
// main kernel helpers: compile-time pair selection; packed f16 math.
// window words W_j = f16 pair (2j, 2j+1) of the shifted row slice.
// ---------------------------------------------------------------------------
template<int J>
__device__ __forceinline__ unsigned wword(const u2v b0, const u2v b1, const u2v b2) {
    if constexpr (J < 2)      return b0[J];
    else if constexpr (J < 4) return b1[J - 2];
    else                      return b2[J - 4];
}

template<int OFF2, int Q>
__device__ __forceinline__ h2v wpair(const u2v b0, const u2v b1, const u2v b2) {
    constexpr int idx0 = OFF2 + 2 * Q;
    constexpr int wj = idx0 >> 1;
    unsigned u;
    if constexpr ((idx0 & 1) == 0)
        u = wword<wj>(b0, b1, b2);
    else
        u = __builtin_amdgcn_alignbit(wword<wj + 1>(b0, b1, b2),
                                      wword<wj>(b0, b1, b2), 16);
    union { unsigned u; h2v h; } X; X.u = u; return X.h;
}

template<int S, int Q, int OFF2>
__device__ __forceinline__ h2v mkpair(const h2v (&xp)[4], int kg,
                                      const u2v b0, const u2v b1, const u2v b2) {
    if constexpr (S == 0) {
        return xp[Q] * xp[Q];                    // squares: window == own slice
    } else {
        const h2v wp = wpair<OFF2, Q>(b0, b1, b2);
        if constexpr (S == 16) {
            return (kg < 2) ? (h2v)(xp[Q] * wp) : wp;   // pairs | linear(x factor in wp)
        } else if constexpr (S == 17) {
            const h2v z = { (_Float16)0.f, (_Float16)0.f };
            return (kg < 2) ? wp : z;                    // linear | pad
        } else {
            return xp[Q] * wp;
        }
    }
}

// ---------------------------------------------------------------------------
// main: block = 64 pts x 256 cl, 4 waves, wave tile 32x128, acc[2][8]=64 AGPR.
// R11 structure (reg-resident B from L2-hot G, no K-loop barriers, per-step
// sched_barrier) + R12: ALL f16. A-gen = 4 v_pk_mul_f16 (+4 alignbit on odd
// shifts) per fragment -- ~1/3 of the bf16 extract/mul/cvt path that made
// VALUBusy the critical pipe (51% vs MfmaUtil 25% in R11).
// ---------------------------------------------------------------------------
template<int S>
__device__ __forceinline__ void k_step(
    const short* __restrict__ gw,      // G + wc*4096 + lane*8 (shorts)
    const short* __restrict__ Xh,
    const int (&rowh)[2],
    const h2v (&xp)[2][4],
    f16x8 (&bf)[8],
    f32x4 (&acc)[2][8],
    int kg)
{
    constexpr int shv  = (S == 17) ? 16 : S;
    constexpr int off2 = shv & 3;
    const int bq = ((kg * 8 + shv) & 31) & ~3;   // aligned 4-half base

    f16x8 af[2];
    #pragma unroll
    for (int i = 0; i < 2; ++i) {
        u2v b0 = {}, b1 = {}, b2 = {};
        if constexpr (S != 0) {
            const short* xr = Xh + rowh[i] + bq;
            b0 = *(const u2v*)(xr);
            b1 = *(const u2v*)(xr + 4);
            if constexpr (off2 != 0) b2 = *(const u2v*)(xr + 8);
        }
        union { f16x8 v; h2v p[4]; } U;
        U.p[0] = mkpair<S, 0, off2>(xp[i], kg, b0, b1, b2);
        U.p[1] = mkpair<S, 1, off2>(xp[i], kg, b0, b1, b2);
        U.p[2] = mkpair<S, 2, off2>(xp[i], kg, b0, b1, b2);
        U.p[3] = mkpair<S, 3, off2>(xp[i], kg, b0, b1, b2);
        af[i] = U.v;
    }

    #pragma unroll
    for (int i = 0; i < 2; ++i)
        #pragma unroll
        for (int j = 0; j < 8; ++j)
            acc[i][j] = __builtin_amdgcn_mfma_f32_16x16x32_f16(
                af[i], bf[j], acc[i][j], 0, 0, 0);

    // bf now dead -> refill with next step's fragments (L1/L2-hot global)
    if constexpr (S + 1 < NSTEP) {
        #pragma unroll
        for (int j = 0; j < 8; ++j)
            bf[j] = *(const f16x8*)(gw + (size_t)(S + 1) * 8192 + j * 512);
    }
    __builtin_amdgcn_sched_barrier(0);   // keep step regions separate (R7 lesson)
}

template<int S>
__device__ __forceinline__ void k_loop(
    const short* __restrict__ gw, const short* __restrict__ Xh,
    const int (&rowh)[2], const h2v (&xp)[2][4],
    f16x8 (&bf)[8], f32x4 (&acc)[2][8], int kg)
{
    k_step<S>(gw, Xh, rowh, xp, bf, acc, kg);
    if constexpr (S + 1 < NSTEP)
        k_loop<S + 1>(gw, Xh, rowh, xp, bf, acc, kg);
}

__global__ __launch_bounds__(THREADS, 3) void gmm_mfma(
    const float* __restrict__ X,
    const short* __restrict__ G,
    const float* __restrict__ cstw,
    const float* __restrict__ thr,
    float* __restrict__ out)
{
    __shared__ __attribute__((aligned(16))) short Xh[BPTS * 44]; // 5.5 KB (f16)
    __shared__ float nrm_s[BPTS];
    __shared__ float cst_s[MCL];
    __shared__ float lse_m[BPTS];
    __shared__ float lse_d[BPTS];

    const int tid  = threadIdx.x;
    const int lane = tid & 63;
    const int w    = tid >> 6;     // wave 0..3
    const int wr   = w & 1;        // row half: 32 points
    const int wc   = w >> 1;       // col half: 128 clusters
    const int r    = lane & 15;
    const int kg   = lane >> 4;
    const int P0   = blockIdx.x * BPTS;

    // per-wave B pointer: cols wc*128.., this lane's 8 f16
    const short* gw = G + wc * 4096 + lane * 8;

    // resident x-slices -> packed f16 pairs xp[i][q] = (x[kg*8+2q], x[kg*8+2q+1])
    int rowh[2];
    h2v xp[2][4];
    #pragma unroll
    for (int i = 0; i < 2; ++i) {
        const int row = wr * 32 + i * 16 + r;
        rowh[i] = row * 44;
        const float4* xg = reinterpret_cast<const float4*>(
            X + (size_t)(P0 + row) * DIM + kg * 8);
        const float4 a = xg[0], b = xg[1];
        xp[i][0] = h2v{ (_Float16)a.x, (_Float16)a.y };
        xp[i][1] = h2v{ (_Float16)a.z, (_Float16)a.w };
        xp[i][2] = h2v{ (_Float16)b.x, (_Float16)b.y };
        xp[i][3] = h2v{ (_Float16)b.z, (_Float16)b.w };
    }

    // stage Xh (f16, +8 dup for circular wrap) + row norms (64 rows, tid<128)
    {
        const int p = tid >> 1, hf = tid & 1;
        if (tid < 128) {
            const float4* Xg = reinterpret_cast<const float4*>(
                X + (size_t)(P0 + p) * DIM + hf * 16);
            float part = 0.f;
            #pragma unroll
            for (int q = 0; q < 4; ++q) {
                const float4 v = Xg[q];
                const int kb = hf * 16 + 4 * q;
                Xh[p * 44 + kb + 0] = f2h(v.x);
                Xh[p * 44 + kb + 1] = f2h(v.y);
                Xh[p * 44 + kb + 2] = f2h(v.z);
                Xh[p * 44 + kb + 3] = f2h(v.w);
                if (!hf && q < 2) {
                    Xh[p * 44 + 32 + kb + 0] = f2h(v.x);
                    Xh[p * 44 + 32 + kb + 1] = f2h(v.y);
                    Xh[p * 44 + 32 + kb + 2] = f2h(v.z);
                    Xh[p * 44 + 32 + kb + 3] = f2h(v.w);
                }
                part = fmaf(v.x, v.x, part); part = fmaf(v.y, v.y, part);
                part = fmaf(v.z, v.z, part); part = fmaf(v.w, v.w, part);
            }
            part += __shfl_xor(part, 1, 64);
            if (!hf) nrm_s[p] = part;
        }
        cst_s[tid] = cstw[tid];
    }

    // prologue: load step-0 B fragments into registers
    f16x8 bf[8];
    #pragma unroll
    for (int j = 0; j < 8; ++j)
        bf[j] = *(const f16x8*)(gw + j * 512);

    __syncthreads();   // Xh/nrm/cst visible to all waves

    f32x4 acc[2][8] = {};
    k_loop<0>(gw, Xh, rowh, xp, bf, acc, kg);

    // ---- epilogue: weighted LSE over this wave's 128 clusters.
    // Butterfly the MAX first (4 stages), then ONE exp pass + butterfly-add:
    // 64 exp/thread instead of R11's 128.
    float cstr[8];
    #pragma unroll
    for (int j = 0; j < 8; ++j)
        cstr[j] = cst_s[wc * 128 + j * 16 + r];

    float mx[8], sm[8];
    #pragma unroll
    for (int i = 0; i < 2; ++i)
        #pragma unroll
        for (int rg = 0; rg < 4; ++rg) {
            const int sl = i * 4 + rg;
            float m_ = -1e30f;
            #pragma unroll
            for (int j = 0; j < 8; ++j)
                m_ = fmaxf(m_, fmaf(acc[i][j][rg], -0.5f, cstr[j]));
            #pragma unroll
            for (int d = 1; d < 16; d <<= 1)
                m_ = fmaxf(m_, __shfl_xor(m_, d, 64));
            float s_ = 0.f;
            #pragma unroll
            for (int j = 0; j < 8; ++j)
                s_ += __expf(fmaf(acc[i][j][rg], -0.5f, cstr[j]) - m_);
            #pragma unroll
            for (int d = 1; d < 16; d <<= 1)
                s_ += __shfl_xor(s_, d, 64);
            mx[sl] = m_; sm[sl] = s_;
        }

    // cross col-half merge via LDS
    if (wc == 0 && r == 0) {
        #pragma unroll
        for (int i = 0; i < 2; ++i)
            #pragma unroll
            for (int rg = 0; rg < 4; ++rg) {
                const int p2 = wr * 32 + i * 16 + kg * 4 + rg;
                lse_m[p2] = mx[i * 4 + rg];
                lse_d[p2] = sm[i * 4 + rg];
            }
    }
    __syncthreads();
    if (wc == 1 && r == 0) {
        const float thrv = thr[0];
        #pragma unroll
        for (int i = 0; i < 2; ++i)
            #pragma unroll
            for (int rg = 0; rg < 4; ++rg) {
                const int sl = i * 4 + rg;
                const int p2 = wr * 32 + i * 16 + kg * 4 + rg;
                const float om = lse_m[p2], os = lse_d[p2];
                const float nm = fmaxf(mx[sl], om);
                const float ss = sm[sl] * __expf(mx[sl] - nm) + os * __expf(om - nm);
                out[P0 + p2] = nm + __logf(ss) - 0.5f * nrm_s[p2] - thrv;
            }
    }
}

extern "C" void kernel_launch(void* const* d_in, const int* in_sizes, int n_in,
                              void* d_out, int out_size, void* d_ws, size_t ws_size,
                              hipStream_t stream)
{
    const float* X      = (const float*)d_in[0];
    const float* center = (const float*)d_in[1];
    const float* L      = (const float*)d_in[2];
    const float* weight = (const float*)d_in[3];
    const float* thr    = (const float*)d_in[4];
    float* out = (float*)d_out;

    // ws layout: cst [256] f32 | G [18*8192] f16-as-short (~296 KB)
    float* cst = (float*)d_ws;
    short* G   = (short*)((char*)d_ws + 1024);

    gmm_prep<<<MCL, 256, 0, stream>>>(center, L, weight, G, cst);
    gmm_mfma<<<NPTS / BPTS, THREADS, 0, stream>>>(X, G, cst, thr, out);
}

// Round 13
// 68.665 us; speedup vs baseline: 5.6947x; 1.0019x over previous
//
#include <hip/hip_runtime.h>
#include <hip/hip_bf16.h>
#include <math.h>

#define NPTS 131072
#define DIM 32
#define MCL 256
#define NSTEP 18           // symmetric packing: 1 sq + 15 pair + 1 pair/lin + 1 lin/pad
#define BPTS 64            // points per block
#define THREADS 256

typedef __attribute__((ext_vector_type(8))) _Float16 f16x8;   // MFMA A/B fragment
typedef __attribute__((ext_vector_type(2))) _Float16 h2v;     // packed f16 pair
typedef __attribute__((ext_vector_type(2))) unsigned u2v;     // 2 dwords (4 f16)
typedef __attribute__((ext_vector_type(4))) float f32x4;

__device__ __forceinline__ short f2h(float f) {
    _Float16 h = (_Float16)f;
    union { _Float16 h; short s; } X; X.h = h; return X.s;
}

// ---------------------------------------------------------------------------
// prep (256 threads/cluster): symmetric-packed G (f16):
//  step 0           : c = E[k][k]                (squares; E = LL^T - I)
//  steps 1..15      : c = 2*E[k][(k+s)&31]       (pairs, circular diff s)
//  step 16, k<16    : c = 2*E[k][k+16]           (diff-16 pairs)
//  step 16, k>=16   : c = -2*Ac[k-16]            (linear)
//  step 17, k<16    : c = -2*Ac[k+16]            (linear)
//  step 17, k>=16   : c = 0                      (pad)
// G addr (shorts): s*8192 + (m>>4)*512 + (k>>3)*128 + (m&15)*8 + (k&7)
// logdet: register GE on wave 0 (col-per-lane, unrolled, no pivot).
// ---------------------------------------------------------------------------
__global__ __launch_bounds__(256) void gmm_prep(
    const float* __restrict__ center,
    const float* __restrict__ L,
    const float* __restrict__ weight,
    short* __restrict__ G,
    float* __restrict__ cst)
{
    const int m = blockIdx.x;
    const int t = threadIdx.x;
    __shared__ float Ls[DIM][DIM + 1];
    __shared__ float As[DIM][DIM + 1];
    __shared__ float Acs[DIM];
    __shared__ float red[DIM];

    const float* Lm = L + m * DIM * DIM;
    for (int k = t; k < DIM * DIM; k += 256)
        Ls[k >> 5][k & 31] = Lm[k];
    __syncthreads();

    // A = L L^T  (4 elems/thread)
    for (int idx = t; idx < DIM * DIM; idx += 256) {
        const int j = idx >> 5, l = idx & 31;
        float a = 0.f;
        #pragma unroll
        for (int d = 0; d < DIM; ++d) a = fmaf(Ls[j][d], Ls[l][d], a);
        As[j][l] = a;
    }
    __syncthreads();

    if (t < DIM) {
        float a = 0.f;
        #pragma unroll
        for (int l = 0; l < DIM; ++l) a = fmaf(As[t][l], center[m * DIM + l], a);
        Acs[t] = a;
        red[t] = a * center[m * DIM + t];
    }
    __syncthreads();

    const int mt = m >> 4, ml = m & 15;
    for (int idx = t; idx < NSTEP * 32; idx += 256) {
        const int s = idx >> 5, k = idx & 31;
        float c;
        if (s == 0)       c = As[k][k] - 1.0f;
        else if (s <= 15) c = 2.0f * As[k][(k + s) & 31];
        else if (s == 16) c = (k < 16) ? 2.0f * As[k][k + 16] : -2.0f * Acs[k - 16];
        else              c = (k < 16) ? -2.0f * Acs[k + 16] : 0.0f;
        G[s * 8192 + mt * 512 + (k >> 3) * 128 + ml * 8 + (k & 7)] = f2h(c);
    }

    if (t < 64) {
        // register GE, no pivot: lane j owns column j.
        float logdet = 0.f;
        if (t < DIM) {
            float col[DIM];
            #pragma unroll
            for (int r2 = 0; r2 < DIM; ++r2) col[r2] = Ls[r2][t];
            float prodabs = 1.0f;
            #pragma unroll
            for (int k = 0; k < DIM; ++k) {
                const float pv  = __shfl(col[k], k, 64);
                const float rpv = 1.0f / pv;
                const float cjk = col[k];
                #pragma unroll
                for (int t2 = k + 1; t2 < DIM; ++t2) {
                    const float f = __shfl(col[t2], k, 64) * rpv;
                    col[t2] = fmaf(-f, cjk, col[t2]);
                }
                prodabs *= fabsf(pv);
            }
            logdet = logf(prodabs);
        }

        float wsp = 0.f;
        for (int j = t; j < MCL; j += 64) wsp += fabsf(weight[j]);
        #pragma unroll
        for (int d2 = 1; d2 < 64; d2 <<= 1) wsp += __shfl_xor(wsp, d2, 64);

        if (t == 0) {
            float t3 = 0.f;
            #pragma unroll
            for (int j = 0; j < DIM; ++j) t3 += red[j];
            cst[m] = logf(fabsf(weight[m])) - logf(wsp) + logdet - 0.5f * t3;
        }
    }
}

// ---------------------------------------------------------------------------
// main kernel helpers: compile-time pair selection; packed f16 math.
// ---------------------------------------------------------------------------
template<int J>
__device__ __forceinline__ unsigned wword(const u2v b0, const u2v b1, const u2v b2) {
    if constexpr (J < 2)      return b0[J];
    else if constexpr (J < 4) return b1[J - 2];
    else                      return b2[J - 4];
}

template<int OFF2, int Q>
__device__ __forceinline__ h2v wpair(const u2v b0, const u2v b1, const u2v b2) {
    constexpr int idx0 = OFF2 + 2 * Q;
    constexpr int wj = idx0 >> 1;
    unsigned u;
    if constexpr ((idx0 & 1) == 0)
        u = wword<wj>(b0, b1, b2);
    else
        u = __builtin_amdgcn_alignbit(wword<wj + 1>(b0, b1, b2),
                                      wword<wj>(b0, b1, b2), 16);
    union { unsigned u; h2v h; } X; X.u = u; return X.h;
}

template<int S, int Q, int OFF2>
__device__ __forceinline__ h2v mkpair(const h2v (&xp)[4], int kg,
                                      const u2v b0, const u2v b1, const u2v b2) {
    if constexpr (S == 0) {
        return xp[Q] * xp[Q];                    // squares: window == own slice
    } else {
        const h2v wp = wpair<OFF2, Q>(b0, b1, b2);
        if constexpr (S == 16) {
            return (kg < 2) ? (h2v)(xp[Q] * wp) : wp;   // pairs | linear
        } else if constexpr (S == 17) {
            const h2v z = { (_Float16)0.f, (_Float16)0.f };
            return (kg < 2) ? wp : z;                    // linear | pad
        } else {
            return xp[Q] * wp;
        }
    }
}

// ---------------------------------------------------------------------------
// main: block = 64 pts x 256 cl, 4 waves, wave tile 32x128, acc[2][8]=64 AGPR.
// R12 structure + R13: DOUBLE-BUFFERED reg-resident B. Step S prefetches
// step S+1's fragments into the buffer not in use (no WAR -> scheduler
// issues the 8 loads BEFORE the MFMAs), giving the loads a full step
// (~700 cyc) to land instead of R12's ~50 cyc. Per-step sched_barrier(0)
// still pins regions (R7 lesson). Reg budget: 104 VGPR + 64 AGPR = 168
// <= 170 cap at 3 waves/SIMD (R8 lesson: checked BEFORE launching).
// ---------------------------------------------------------------------------
template<int S>
__device__ __forceinline__ void k_step(
    const short* __restrict__ gw,      // G + wc*4096 + lane*8 (shorts)
    const short* __restrict__ Xh,
    const int (&rowh)[2],
    const h2v (&xp)[2][4],
    f16x8 (&bfA)[8], f16x8 (&bfB)[8],
    f32x4 (&acc)[2][8],
    int kg)
{
    f16x8 (&cur)[8] = ((S & 1) == 0) ? bfA : bfB;
    f16x8 (&nxt)[8] = ((S & 1) == 0) ? bfB : bfA;

    // prefetch S+1 into the idle buffer (source-first; no WAR vs this step's
    // MFMAs, so the scheduler can issue these before/among them)
    if constexpr (S + 1 < NSTEP) {
        #pragma unroll
        for (int j = 0; j < 8; ++j)
            nxt[j] = *(const f16x8*)(gw + (size_t)(S + 1) * 8192 + j * 512);
    }

    constexpr int shv  = (S == 17) ? 16 : S;
    constexpr int off2 = shv & 3;
    const int bq = ((kg * 8 + shv) & 31) & ~3;   // aligned 4-half base

    f16x8 af[2];
    #pragma unroll
    for (int i = 0; i < 2; ++i) {
        u2v b0 = {}, b1 = {}, b2 = {};
        if constexpr (S != 0) {
            const short* xr = Xh + rowh[i] + bq;
            b0 = *(const u2v*)(xr);
            b1 = *(const u2v*)(xr + 4);
            if constexpr (off2 != 0) b2 = *(const u2v*)(xr + 8);
        }
        union { f16x8 v; h2v p[4]; } U;
        U.p[0] = mkpair<S, 0, off2>(xp[i], kg, b0, b1, b2);
        U.p[1] = mkpair<S, 1, off2>(xp[i], kg, b0, b1, b2);
        U.p[2] = mkpair<S, 2, off2>(xp[i], kg, b0, b1, b2);
        U.p[3] = mkpair<S, 3, off2>(xp[i], kg, b0, b1, b2);
        af[i] = U.v;
    }

    #pragma unroll
    for (int i = 0; i < 2; ++i)
        #pragma unroll
        for (int j = 0; j < 8; ++j)
            acc[i][j] = __builtin_amdgcn_mfma_f32_16x16x32_f16(
                af[i], cur[j], acc[i][j], 0, 0, 0);

    __builtin_amdgcn_sched_barrier(0);   // keep step regions separate (R7 lesson)
}

template<int S>
__device__ __forceinline__ void k_loop(
    const short* __restrict__ gw, const short* __restrict__ Xh,
    const int (&rowh)[2], const h2v (&xp)[2][4],
    f16x8 (&bfA)[8], f16x8 (&bfB)[8], f32x4 (&acc)[2][8], int kg)
{
    k_step<S>(gw, Xh, rowh, xp, bfA, bfB, acc, kg);
    if constexpr (S + 1 < NSTEP)
        k_loop<S + 1>(gw, Xh, rowh, xp, bfA, bfB, acc, kg);
}

__global__ __launch_bounds__(THREADS, 3) void gmm_mfma(
    const float* __restrict__ X,
    const short* __restrict__ G,
    const float* __restrict__ cstw,
    const float* __restrict__ thr,
    float* __restrict__ out)
{
    __shared__ __attribute__((aligned(16))) short Xh[BPTS * 44]; // 5.5 KB (f16)
    __shared__ float nrm_s[BPTS];
    __shared__ float cst_s[MCL];
    __shared__ float lse_m[BPTS];
    __shared__ float lse_d[BPTS];

    const int tid  = threadIdx.x;
    const int lane = tid & 63;
    const int w    = tid >> 6;     // wave 0..3
    const int wr   = w & 1;        // row half: 32 points
    const int wc   = w >> 1;       // col half: 128 clusters
    const int r    = lane & 15;
    const int kg   = lane >> 4;
    const int P0   = blockIdx.x * BPTS;

    // per-wave B pointer: cols wc*128.., this lane's 8 f16
    const short* gw = G + wc * 4096 + lane * 8;

    // resident x-slices -> packed f16 pairs
    int rowh[2];
    h2v xp[2][4];
    #pragma unroll
    for (int i = 0; i < 2; ++i) {
        const int row = wr * 32 + i * 16 + r;
        rowh[i] = row * 44;
        const float4* xg = reinterpret_cast<const float4*>(
            X + (size_t)(P0 + row) * DIM + kg * 8);
        const float4 a = xg[0], b = xg[1];
        xp[i][0] = h2v{ (_Float16)a.x, (_Float16)a.y };
        xp[i][1] = h2v{ (_Float16)a.z, (_Float16)a.w };
        xp[i][2] = h2v{ (_Float16)b.x, (_Float16)b.y };
        xp[i][3] = h2v{ (_Float16)b.z, (_Float16)b.w };
    }

    // stage Xh (f16, +8 dup for circular wrap) + row norms (64 rows, tid<128)
    {
        const int p = tid >> 1, hf = tid & 1;
        if (tid < 128) {
            const float4* Xg = reinterpret_cast<const float4*>(
                X + (size_t)(P0 + p) * DIM + hf * 16);
            float part = 0.f;
            #pragma unroll
            for (int q = 0; q < 4; ++q) {
                const float4 v = Xg[q];
                const int kb = hf * 16 + 4 * q;
                Xh[p * 44 + kb + 0] = f2h(v.x);
                Xh[p * 44 + kb + 1] = f2h(v.y);
                Xh[p * 44 + kb + 2] = f2h(v.z);
                Xh[p * 44 + kb + 3] = f2h(v.w);
                if (!hf && q < 2) {
                    Xh[p * 44 + 32 + kb + 0] = f2h(v.x);
                    Xh[p * 44 + 32 + kb + 1] = f2h(v.y);
                    Xh[p * 44 + 32 + kb + 2] = f2h(v.z);
                    Xh[p * 44 + 32 + kb + 3] = f2h(v.w);
                }
                part = fmaf(v.x, v.x, part); part = fmaf(v.y, v.y, part);
                part = fmaf(v.z, v.z, part); part = fmaf(v.w, v.w, part);
            }
            part += __shfl_xor(part, 1, 64);
            if (!hf) nrm_s[p] = part;
        }
        cst_s[tid] = cstw[tid];
    }

    // prologue: load step-0 B fragments into buffer A
    f16x8 bfA[8], bfB[8];
    #pragma unroll
    for (int j = 0; j < 8; ++j)
        bfA[j] = *(const f16x8*)(gw + j * 512);

    __syncthreads();   // Xh/nrm/cst visible to all waves

    f32x4 acc[2][8] = {};
    k_loop<0>(gw, Xh, rowh, xp, bfA, bfB, acc, kg);

    // ---- epilogue: weighted LSE over this wave's 128 clusters.
    float cstr[8];
    #pragma unroll
    for (int j = 0; j < 8; ++j)
        cstr[j] = cst_s[wc * 128 + j * 16 + r];

    float mx[8], sm[8];
    #pragma unroll
    for (int i = 0; i < 2; ++i)
        #pragma unroll
        for (int rg = 0; rg < 4; ++rg) {
            const int sl = i * 4 + rg;
            float m_ = -1e30f;
            #pragma unroll
            for (int j = 0; j < 8; ++j)
                m_ = fmaxf(m_, fmaf(acc[i][j][rg], -0.5f, cstr[j]));
            #pragma unroll
            for (int d = 1; d < 16; d <<= 1)
                m_ = fmaxf(m_, __shfl_xor(m_, d, 64));
            float s_ = 0.f;
            #pragma unroll
            for (int j = 0; j < 8; ++j)
                s_ += __expf(fmaf(acc[i][j][rg], -0.5f, cstr[j]) - m_);
            #pragma unroll
            for (int d = 1; d < 16; d <<= 1)
                s_ += __shfl_xor(s_, d, 64);
            mx[sl] = m_; sm[sl] = s_;
        }

    // cross col-half merge via LDS
    if (wc == 0 && r == 0) {
        #pragma unroll
        for (int i = 0; i < 2; ++i)
            #pragma unroll
            for (int rg = 0; rg < 4; ++rg) {
                const int p2 = wr * 32 + i * 16 + kg * 4 + rg;
                lse_m[p2] = mx[i * 4 + rg];
                lse_d[p2] = sm[i * 4 + rg];
            }
    }
    __syncthreads();
    if (wc == 1 && r == 0) {
        const float thrv = thr[0];
        #pragma unroll
        for (int i = 0; i < 2; ++i)
            #pragma unroll
            for (int rg = 0; rg < 4; ++rg) {
                const int sl = i * 4 + rg;
                const int p2 = wr * 32 + i * 16 + kg * 4 + rg;
                const float om = lse_m[p2], os = lse_d[p2];
                const float nm = fmaxf(mx[sl], om);
                const float ss = sm[sl] * __expf(mx[sl] - nm) + os * __expf(om - nm);
                out[P0 + p2] = nm + __logf(ss) - 0.5f * nrm_s[p2] - thrv;
            }
    }
}

extern "C" void kernel_launch(void* const* d_in, const int* in_sizes, int n_in,
                              void* d_out, int out_size, void* d_ws, size_t ws_size,
                              hipStream_t stream)
{
    const float* X      = (const float*)d_in[0];
    const float* center = (const float*)d_in[1];
    const float* L      = (const float*)d_in[2];
    const float* weight = (const float*)d_in[3];
    const float* thr    = (const float*)d_in[4];
    float* out = (float*)d_out;

    // ws layout: cst [256] f32 | G [18*8192] f16-as-short (~296 KB)
    float* cst = (float*)d_ws;
    short* G   = (short*)((char*)d_ws + 1024);

    gmm_prep<<<MCL, 256, 0, stream>>>(center, L, weight, G, cst);
    gmm_mfma<<<NPTS / BPTS, THREADS, 0, stream>>>(X, G, cst, thr, out);
}